// Round 6
// baseline (861.573 us; speedup 1.0000x reference)
//
#include <hip/hip_runtime.h>
#include <hip/hip_bf16.h>
#include <cstdint>
#include <cstddef>

#define KEYSHIFT 20
#define COLMASK 0xFFFFFu
#define EPB 8192    // edges per count/scatter block (1024 threads x 8)
#define SUB 4096    // staged sub-chunk inside scatter (fits 54KB LDS)
#define BSHIFT 8    // 256 rows per bucket
#define NRB 256     // rows per bucket (1 << BSHIFT)
#define CCAP 3072   // LDS sort capacity per bucket (avg ~2560, max ~2750)

// bf16 pack/unpack: gathered operand is bf16 (halves the L2-miss fill
// traffic); all accumulation stays fp32.
__device__ __forceinline__ unsigned short f2bf(float f) {
    uint32_t u = __float_as_uint(f);
    u += ((u >> 16) & 1u) + 0x7fffu;   // RNE
    return (unsigned short)(u >> 16);
}
__device__ __forceinline__ float bf2f(unsigned short h) {
    return __uint_as_float(((uint32_t)h) << 16);
}

// ---------------------------------------------------------------------------
// Host-side reproduction of np.random.RandomState(2).permutation(64):
// MT19937 init_genrand(2), Fisher-Yates with numpy random_interval
// (mask+rejection). Mask bit d = (perm[d] >= 38).
// ---------------------------------------------------------------------------
static uint64_t compute_mask_bits() {
    uint32_t mt[624];
    mt[0] = 2u;
    for (int i = 1; i < 624; i++)
        mt[i] = 1812433253u * (mt[i - 1] ^ (mt[i - 1] >> 30)) + (uint32_t)i;
    int mti = 624;
    auto genrand = [&]() -> uint32_t {
        if (mti >= 624) {
            for (int k = 0; k < 624; k++) {
                uint32_t y = (mt[k] & 0x80000000u) | (mt[(k + 1) % 624] & 0x7fffffffu);
                mt[k] = mt[(k + 397) % 624] ^ (y >> 1) ^ ((y & 1u) ? 2567483615u : 0u);
            }
            mti = 0;
        }
        uint32_t y = mt[mti++];
        y ^= y >> 11;
        y ^= (y << 7) & 2636928640u;
        y ^= (y << 15) & 4022730752u;
        y ^= y >> 18;
        return y;
    };
    int arr[64];
    for (int i = 0; i < 64; i++) arr[i] = i;
    for (int i = 63; i >= 1; i--) {
        uint32_t mask = (uint32_t)i;
        mask |= mask >> 1; mask |= mask >> 2; mask |= mask >> 4;
        mask |= mask >> 8; mask |= mask >> 16;
        uint32_t v;
        do { v = genrand() & mask; } while (v > (uint32_t)i);
        int tmp = arr[i]; arr[i] = arr[v]; arr[v] = tmp;
    }
    uint64_t bits = 0;
    for (int d = 0; d < 64; d++)
        if (arr[d] >= 38) bits |= (1ull << d);
    return bits;
}

// ---------------------------------------------------------------------------
// Output-row flag set + compacted list (rows read by the final dot).
// ---------------------------------------------------------------------------
__global__ void flag_kernel(const int* __restrict__ users, const int* __restrict__ items,
                            unsigned char* __restrict__ flag, int B, int U) {
    int i = blockIdx.x * 256 + threadIdx.x;
    if (i < B) flag[users[i]] = 1;
    else if (i < 2 * B) flag[U + items[i - B]] = 1;
}

__global__ void flist_kernel(const unsigned char* __restrict__ flag,
                             int* __restrict__ flist, int* __restrict__ fcount, int n) {
    int i = blockIdx.x * 256 + threadIdx.x;
    if (i < n && flag[i]) {
        int p = atomicAdd(fcount, 1);
        flist[p] = i;
    }
}

// ---------------------------------------------------------------------------
// Per-rating constant c1[r][j] = b1[r][j] + sum_k e_r[k] * W1[r][64+k][j].
// ---------------------------------------------------------------------------
__global__ void c1_kernel(const float* __restrict__ rating_emb, const float* __restrict__ W1,
                          const float* __restrict__ b1, float* __restrict__ c1_all) {
    int r = blockIdx.x;
    int t = threadIdx.x;  // 64 threads
    const float* W1r = W1 + (size_t)r * (128 * 64);
    float acc = b1[r * 64 + t];
    for (int k = 0; k < 64; k++)
        acc += rating_emb[r * 64 + k] * W1r[(64 + k) * 64 + t];
    c1_all[r * 64 + t] = acc;
}

// ---------------------------------------------------------------------------
// Build pass A (batched over ratings): LDS histogram over K=ceil(N/256) row
// buckets, then ONE global atomicAdd per (block,bucket) to reserve a range.
// ---------------------------------------------------------------------------
__global__ __launch_bounds__(1024) void bucket_count_kernel(
    const int* __restrict__ rows, int* __restrict__ gcnt,
    int* __restrict__ blockBase, int E, int K, int nb) {
    __shared__ int hist[2048];
    int r = blockIdx.y, blk = blockIdx.x, t = threadIdx.x;
    for (int i = t; i < K; i += 1024) hist[i] = 0;
    __syncthreads();
    size_t base = (size_t)r * E + (size_t)blk * EPB;
    int cnt = E - blk * EPB;
    if (cnt > EPB) cnt = EPB;
    for (int k = t; k < cnt; k += 1024)
        atomicAdd(&hist[rows[base + k] >> BSHIFT], 1);
    __syncthreads();
    for (int i = t; i < K; i += 1024) {
        int c = hist[i];
        int bb = (c > 0) ? atomicAdd(&gcnt[r * K + i], c) : 0;
        blockBase[((size_t)r * nb + blk) * K + i] = bb;
    }
}

// ---------------------------------------------------------------------------
// Exclusive scan of K bucket counts -> bptr[K+1] per rating (grid.x = R).
// ---------------------------------------------------------------------------
__global__ void bucket_scan_kernel(const int* __restrict__ gcnt,
                                   int* __restrict__ bptr, int K) {
    __shared__ int sh[256];
    int r = blockIdx.x;
    int t = threadIdx.x;
    int base = t * 8;
    int v[8];
    int s = 0;
    #pragma unroll
    for (int j = 0; j < 8; j++) {
        int idx = base + j;
        v[j] = (idx < K) ? gcnt[r * K + idx] : 0;
        s += v[j];
    }
    sh[t] = s;
    __syncthreads();
    for (int off = 1; off < 256; off <<= 1) {
        int x = (t >= off) ? sh[t - off] : 0;
        __syncthreads();
        sh[t] += x;
        __syncthreads();
    }
    int run = sh[t] - s;
    #pragma unroll
    for (int j = 0; j < 8; j++) {
        int idx = base + j;
        if (idx <= K) bptr[r * (K + 1) + idx] = run;
        run += v[j];
    }
}

// ---------------------------------------------------------------------------
// Build pass B: LDS-STAGED scatter into bucket-grouped rec (K <= 512).
// Each 4096-edge sub-chunk is histogrammed, scanned, staged bucket-grouped
// in LDS with its final global address, then written out linearly.
// ---------------------------------------------------------------------------
__global__ __launch_bounds__(1024) void bucket_scatter_kernel(
    const int* __restrict__ rows, const int* __restrict__ cols,
    const float* __restrict__ vals, const int* __restrict__ bptr,
    const int* __restrict__ blockBase, uint2* __restrict__ rec,
    int E, int K, long long eStride, long long pStride,
    long long bbStride, long long rStride) {
    __shared__ uint2 staged[SUB];   // 32KB
    __shared__ int gaddr[SUB];      // 16KB final rec index per staged slot
    __shared__ int cursor[512];     // running global cursor per bucket
    __shared__ int lhist[512];      // per-subchunk count -> local base
    __shared__ int aux[512];        // scan scratch -> goff (=gbase-localbase)
    int r = blockIdx.y;
    const int* rows_r = rows + (size_t)r * eStride;
    const int* cols_r = cols + (size_t)r * eStride;
    const float* vals_r = vals + (size_t)r * eStride;
    const int* bptr_r = bptr + (size_t)r * pStride;
    const int* bb_r = blockBase + (size_t)r * bbStride;
    uint2* rec_r = rec + (size_t)r * rStride;
    int blk = blockIdx.x, t = threadIdx.x;
    if (t < 512)
        cursor[t] = (t < K) ? (bptr_r[t] + bb_r[(size_t)blk * K + t]) : 0;
    size_t base = (size_t)blk * EPB;
    int cnt = E - blk * EPB;
    if (cnt > EPB) cnt = EPB;
    for (int c0 = 0; c0 < cnt; c0 += SUB) {
        int scnt = cnt - c0;
        if (scnt > SUB) scnt = SUB;
        if (t < 512) lhist[t] = 0;
        __syncthreads();
        int bkt_[4], lpos_[4];
        uint2 rv_[4];
        #pragma unroll
        for (int q = 0; q < 4; q++) {
            int kk = (q << 10) + t;
            bkt_[q] = -1;
            if (kk < scnt) {
                size_t g = base + c0 + kk;
                int row = rows_r[g];
                int b = row >> BSHIFT;
                bkt_[q] = b;
                rv_[q] = make_uint2(((uint32_t)(row & (NRB - 1)) << KEYSHIFT) |
                                        (uint32_t)cols_r[g],
                                    __float_as_uint(vals_r[g]));
                lpos_[q] = atomicAdd(&lhist[b], 1);
            }
        }
        __syncthreads();
        int v = (t < 512) ? lhist[t] : 0;
        if (t < 512) aux[t] = v;
        __syncthreads();
        for (int off = 1; off < 512; off <<= 1) {
            int x = 0;
            if (t >= off && t < 512) x = aux[t - off];
            __syncthreads();
            if (t < 512) aux[t] += x;
            __syncthreads();
        }
        if (t < 512) {
            int ex = aux[t] - v;     // exclusive local base
            int gb = cursor[t];      // global base for this sub-chunk
            cursor[t] = gb + v;
            lhist[t] = ex;
            aux[t] = gb - ex;        // goff: gaddr = goff[b] + staged_idx
        }
        __syncthreads();
        #pragma unroll
        for (int q = 0; q < 4; q++) {
            if (bkt_[q] >= 0) {
                int sidx = lhist[bkt_[q]] + lpos_[q];
                staged[sidx] = rv_[q];
                gaddr[sidx] = aux[bkt_[q]] + sidx;
            }
        }
        __syncthreads();
        for (int i = t; i < scnt; i += 1024)
            rec_r[gaddr[i]] = staged[i];
        __syncthreads();
    }
}

// ---------------------------------------------------------------------------
// Build pass B legacy (direct scatter) — only used if K > 512.
// ---------------------------------------------------------------------------
__global__ __launch_bounds__(1024) void bucket_scatter_legacy(
    const int* __restrict__ rows, const int* __restrict__ cols,
    const float* __restrict__ vals, const int* __restrict__ bptr,
    const int* __restrict__ blockBase, uint2* __restrict__ rec,
    int E, int K, long long eStride, long long pStride,
    long long bbStride, long long rStride) {
    __shared__ int cursor[2048];
    int r = blockIdx.y;
    const int* rows_r = rows + (size_t)r * eStride;
    const int* cols_r = cols + (size_t)r * eStride;
    const float* vals_r = vals + (size_t)r * eStride;
    const int* bptr_r = bptr + (size_t)r * pStride;
    const int* bb_r = blockBase + (size_t)r * bbStride;
    uint2* rec_r = rec + (size_t)r * rStride;
    int blk = blockIdx.x, t = threadIdx.x;
    for (int i = t; i < K; i += 1024)
        cursor[i] = bptr_r[i] + bb_r[(size_t)blk * K + i];
    __syncthreads();
    size_t base = (size_t)blk * EPB;
    int cnt = E - blk * EPB;
    if (cnt > EPB) cnt = EPB;
    for (int k = t; k < cnt; k += 1024) {
        int row = rows_r[base + k];
        int b = row >> BSHIFT;
        int pos = atomicAdd(&cursor[b], 1);
        uint32_t key = ((uint32_t)(row & (NRB - 1)) << KEYSHIFT) | (uint32_t)cols_r[base + k];
        rec_r[pos] = make_uint2(key, __float_as_uint(vals_r[base + k]));
    }
}

// ---------------------------------------------------------------------------
// Build pass C: per-bucket counting sort by rel-row, FULLY IN LDS; srec
// written as one dense coalesced stream. Emits row_ptr.
// ---------------------------------------------------------------------------
__global__ __launch_bounds__(256) void bucket_sort_kernel(
    const uint2* __restrict__ rec, uint2* __restrict__ srec,
    const int* __restrict__ bptr, int* __restrict__ rp, int K, int N,
    long long rStride, long long pStride, long long rpStride) {
    __shared__ uint2 staged[CCAP];  // 24KB
    __shared__ int hist[NRB];
    __shared__ int excl[NRB];
    int r = blockIdx.y;
    const uint2* rec_r = rec + (size_t)r * rStride;
    uint2* srec_r = srec + (size_t)r * rStride;
    const int* bptr_r = bptr + (size_t)r * pStride;
    int* rp_r = rp + (size_t)r * rpStride;
    int b = blockIdx.x;
    int t = threadIdx.x;          // 256 threads == NRB
    hist[t] = 0;
    __syncthreads();
    int start = bptr_r[b], end = bptr_r[b + 1];
    int m = end - start;
    for (int e = start + t; e < end; e += 256)
        atomicAdd(&hist[rec_r[e].x >> KEYSHIFT], 1);
    __syncthreads();
    int v = hist[t];
    excl[t] = v;
    __syncthreads();
    for (int off = 1; off < 256; off <<= 1) {
        int x = (t >= off) ? excl[t - off] : 0;
        __syncthreads();
        excl[t] += x;
        __syncthreads();
    }
    int ex = excl[t] - v;
    excl[t] = ex;                 // own-slot overwrite, no cross-read yet
    hist[t] = 0;                  // reuse as cursors
    int row = b * NRB + t;
    if (row < N) rp_r[row] = start + ex;
    if (b == K - 1 && t == 0) rp_r[N] = bptr_r[K];
    __syncthreads();
    if (m <= CCAP) {
        for (int e = start + t; e < end; e += 256) {
            uint2 rr = rec_r[e];
            int rel = (int)(rr.x >> KEYSHIFT);
            int pos = excl[rel] + atomicAdd(&hist[rel], 1);
            staged[pos] = rr;
        }
        __syncthreads();
        for (int i = t; i < m; i += 256)
            srec_r[start + i] = staged[i];
    } else {
        for (int e = start + t; e < end; e += 256) {
            uint2 rr = rec_r[e];
            int rel = (int)(rr.x >> KEYSHIFT);
            int pos = start + excl[rel] + atomicAdd(&hist[rel], 1);
            srec_r[pos] = rr;
        }
    }
}

// ---------------------------------------------------------------------------
// Per-rating MLP: h = leaky_relu(x @ W1a + c1) @ W2 + b2
// R17: LDS-pipe model — R4/R5 both issued 1.6M wave-b128 (2 reads per 16
// FMAs) = ~31us on the single LDS pipe; occupancy was irrelevant. Fix:
// 8x8 per-thread tile, 128 threads / 128 rows: per 4-k step 16 b128 feed
// 256 FMAs -> 800K reads (~16us model). sX[i][k] with XOR chunk swizzle
// (chunk^=(i&7)); rows i=(t>>3)+16a so i&7 varies per lane -> the 8
// x-reads tile all 32 banks. sW natural [k][j]: j-contiguous reads,
// broadcast. fp32 throughout; prev bf16; out_acc fp32.
// ---------------------------------------------------------------------------
__global__ __launch_bounds__(128, 2) void mlp_kernel(
    const float* __restrict__ user_emb, const float* __restrict__ item_emb,
    const float* __restrict__ W1, const float* __restrict__ W2,
    const float* __restrict__ c1_all, const float* __restrict__ b2,
    unsigned short* __restrict__ prev, float* __restrict__ out_acc,
    const unsigned char* __restrict__ flag, int r, int n_rows, int U, int init) {
    __shared__ float sW[64 * 64];    // [k][j], natural (16KB)
    __shared__ float sX[128 * 64];   // [i][k], XOR-chunk swizzled (32KB)
    __shared__ float sc1[64];
    __shared__ float sb2v[64];

    int t = threadIdx.x;
    int row0 = blockIdx.x * 128;
    const float* W1r = W1 + (size_t)r * (128 * 64);
    const float* W2r = W2 + (size_t)r * (64 * 64);
    int g = t >> 3;           // 0..15: row base; rows i = g + 16a
    int j0 = (t & 7) * 8;     // cols j0..j0+7
    int swz = g & 7;          // == (i & 7) for all this thread's rows

    // X tile: 2048 float4 / 128 threads = 16 each; coalesced global read,
    // swizzled LDS store (16 consecutive t share row i, c spans the row).
    #pragma unroll
    for (int q = 0; q < 16; q++) {
        int f = t + 128 * q;
        int i = f >> 4;
        int c = (f & 15) * 4;
        int nrow = row0 + i;
        float4 xv = make_float4(0.f, 0.f, 0.f, 0.f);
        if (nrow < n_rows) {
            const float* src = (nrow < U) ? (user_emb + (size_t)nrow * 64)
                                          : (item_emb + (size_t)(nrow - U) * 64);
            xv = *(const float4*)(src + c);
        }
        *(float4*)(sX + i * 64 + (((c >> 2) ^ (i & 7)) << 2)) = xv;
    }
    // W1a tile: 1024 float4 / 128 threads = 8 each, linear
    #pragma unroll
    for (int q = 0; q < 8; q++) {
        int f = t + 128 * q;
        int k = f >> 4, c = (f & 15) * 4;
        *(float4*)(sW + k * 64 + c) = *(const float4*)(W1r + k * 64 + c);
    }
    if (t < 64) sc1[t] = c1_all[r * 64 + t];
    else sb2v[t - 64] = b2[r * 64 + (t - 64)];
    __syncthreads();

    float acc[8][8];
    #pragma unroll
    for (int a = 0; a < 8; a++)
        #pragma unroll
        for (int b = 0; b < 8; b++) acc[a][b] = sc1[j0 + b];

    // GEMM1: acc += X @ W1a
    for (int k0 = 0; k0 < 64; k0 += 4) {
        int xs = ((k0 >> 2) ^ swz) << 2;
        float4 xv[8];
        #pragma unroll
        for (int a = 0; a < 8; a++)
            xv[a] = *(const float4*)(sX + (g + 16 * a) * 64 + xs);
        float4 wlo[4], whi[4];
        #pragma unroll
        for (int kk = 0; kk < 4; kk++) {
            wlo[kk] = *(const float4*)(sW + (k0 + kk) * 64 + j0);
            whi[kk] = *(const float4*)(sW + (k0 + kk) * 64 + j0 + 4);
        }
        #pragma unroll
        for (int kk = 0; kk < 4; kk++) {
            float wj[8] = {wlo[kk].x, wlo[kk].y, wlo[kk].z, wlo[kk].w,
                           whi[kk].x, whi[kk].y, whi[kk].z, whi[kk].w};
            #pragma unroll
            for (int a = 0; a < 8; a++) {
                float xsc = (kk == 0) ? xv[a].x : (kk == 1) ? xv[a].y
                          : (kk == 2) ? xv[a].z : xv[a].w;
                #pragma unroll
                for (int b = 0; b < 8; b++) acc[a][b] += xsc * wj[b];
            }
        }
    }
    __syncthreads();   // all GEMM1 reads of sX/sW done

    // T = leaky_relu(acc) stored into sX (same swizzled [i][k'] layout)
    #pragma unroll
    for (int a = 0; a < 8; a++) {
        int i = g + 16 * a;
        float4 t0, t1;
        t0.x = (acc[a][0] >= 0.f) ? acc[a][0] : 0.01f * acc[a][0];
        t0.y = (acc[a][1] >= 0.f) ? acc[a][1] : 0.01f * acc[a][1];
        t0.z = (acc[a][2] >= 0.f) ? acc[a][2] : 0.01f * acc[a][2];
        t0.w = (acc[a][3] >= 0.f) ? acc[a][3] : 0.01f * acc[a][3];
        t1.x = (acc[a][4] >= 0.f) ? acc[a][4] : 0.01f * acc[a][4];
        t1.y = (acc[a][5] >= 0.f) ? acc[a][5] : 0.01f * acc[a][5];
        t1.z = (acc[a][6] >= 0.f) ? acc[a][6] : 0.01f * acc[a][6];
        t1.w = (acc[a][7] >= 0.f) ? acc[a][7] : 0.01f * acc[a][7];
        *(float4*)(sX + i * 64 + ((((j0 >> 2) + 0) ^ (i & 7)) << 2)) = t0;
        *(float4*)(sX + i * 64 + ((((j0 >> 2) + 1) ^ (i & 7)) << 2)) = t1;
    }
    #pragma unroll
    for (int q = 0; q < 8; q++) {
        int f = t + 128 * q;
        int k = f >> 4, c = (f & 15) * 4;
        *(float4*)(sW + k * 64 + c) = *(const float4*)(W2r + k * 64 + c);
    }
    __syncthreads();

    #pragma unroll
    for (int a = 0; a < 8; a++)
        #pragma unroll
        for (int b = 0; b < 8; b++) acc[a][b] = sb2v[j0 + b];

    // GEMM2: acc += T @ W2
    for (int k0 = 0; k0 < 64; k0 += 4) {
        int xs = ((k0 >> 2) ^ swz) << 2;
        float4 xv[8];
        #pragma unroll
        for (int a = 0; a < 8; a++)
            xv[a] = *(const float4*)(sX + (g + 16 * a) * 64 + xs);
        float4 wlo[4], whi[4];
        #pragma unroll
        for (int kk = 0; kk < 4; kk++) {
            wlo[kk] = *(const float4*)(sW + (k0 + kk) * 64 + j0);
            whi[kk] = *(const float4*)(sW + (k0 + kk) * 64 + j0 + 4);
        }
        #pragma unroll
        for (int kk = 0; kk < 4; kk++) {
            float wj[8] = {wlo[kk].x, wlo[kk].y, wlo[kk].z, wlo[kk].w,
                           whi[kk].x, whi[kk].y, whi[kk].z, whi[kk].w};
            #pragma unroll
            for (int a = 0; a < 8; a++) {
                float xsc = (kk == 0) ? xv[a].x : (kk == 1) ? xv[a].y
                          : (kk == 2) ? xv[a].z : xv[a].w;
                #pragma unroll
                for (int b = 0; b < 8; b++) acc[a][b] += xsc * wj[b];
            }
        }
    }

    // Epilogue: prev (bf16) + out_acc (fp32, flagged rows)
    #pragma unroll
    for (int a = 0; a < 8; a++) {
        int nrow = row0 + g + 16 * a;
        if (nrow < n_rows) {
            ushort4 h0, h1;
            h0.x = f2bf(acc[a][0]); h0.y = f2bf(acc[a][1]);
            h0.z = f2bf(acc[a][2]); h0.w = f2bf(acc[a][3]);
            h1.x = f2bf(acc[a][4]); h1.y = f2bf(acc[a][5]);
            h1.z = f2bf(acc[a][6]); h1.w = f2bf(acc[a][7]);
            *(ushort4*)(prev + (size_t)nrow * 64 + j0) = h0;
            *(ushort4*)(prev + (size_t)nrow * 64 + j0 + 4) = h1;
            if (flag[nrow]) {
                float* o = out_acc + (size_t)nrow * 64 + j0;
                if (init) {
                    *(float4*)(o + 0) = make_float4(acc[a][0], acc[a][1], acc[a][2], acc[a][3]);
                    *(float4*)(o + 4) = make_float4(acc[a][4], acc[a][5], acc[a][6], acc[a][7]);
                } else {
                    float4 o0 = *(const float4*)(o + 0);
                    float4 o1 = *(const float4*)(o + 4);
                    o0.x += acc[a][0]; o0.y += acc[a][1];
                    o0.z += acc[a][2]; o0.w += acc[a][3];
                    o1.x += acc[a][4]; o1.y += acc[a][5];
                    o1.z += acc[a][6]; o1.w += acc[a][7];
                    *(float4*)(o + 0) = o0;
                    *(float4*)(o + 4) = o1;
                }
            }
        }
    }
}

// ---------------------------------------------------------------------------
// Gather-SpMM (layers 0/1): wave = 1 row; 4 edge-groups x 16 lanes.
// Batched 4-edge window (ILP): 4 rec loads back-to-back, then 4 gathers —
// two dependent memory legs per row. Invalid slots clamp to rec[ew] (L1
// hit) with v=0. Deg~10 -> one 16-edge window covers ~97% of rows.
// ---------------------------------------------------------------------------
__global__ __launch_bounds__(256) void spmm_kernel(
    const unsigned short* __restrict__ prev, unsigned short* __restrict__ next,
    float* __restrict__ out_acc, const int* __restrict__ rp,
    const uint2* __restrict__ rec, const unsigned char* __restrict__ flag, int n) {
    int wave = (int)((blockIdx.x * (unsigned)blockDim.x + threadIdx.x) >> 6);
    int lane = threadIdx.x & 63;
    if (wave >= n) return;
    int sub = lane >> 4;      // edge group 0..3
    int dl = lane & 15;       // dims [dl*4, dl*4+4)
    int s = rp[wave], e2 = rp[wave + 1];
    float ax = 0.f, ay = 0.f, az = 0.f, aw = 0.f;
    for (int ew = s + sub; ew < e2; ew += 16) {
        int i1 = ew + 4, i2 = ew + 8, i3 = ew + 12;
        uint2 r0 = rec[ew];
        uint2 r1 = rec[i1 < e2 ? i1 : ew];
        uint2 r2 = rec[i2 < e2 ? i2 : ew];
        uint2 r3 = rec[i3 < e2 ? i3 : ew];
        float v0 = __uint_as_float(r0.y);
        float v1 = (i1 < e2) ? __uint_as_float(r1.y) : 0.f;
        float v2 = (i2 < e2) ? __uint_as_float(r2.y) : 0.f;
        float v3 = (i3 < e2) ? __uint_as_float(r3.y) : 0.f;
        ushort4 q0 = *(const ushort4*)(prev + (size_t)(r0.x & COLMASK) * 64 + dl * 4);
        ushort4 q1 = *(const ushort4*)(prev + (size_t)(r1.x & COLMASK) * 64 + dl * 4);
        ushort4 q2 = *(const ushort4*)(prev + (size_t)(r2.x & COLMASK) * 64 + dl * 4);
        ushort4 q3 = *(const ushort4*)(prev + (size_t)(r3.x & COLMASK) * 64 + dl * 4);
        ax += v0 * bf2f(q0.x) + v1 * bf2f(q1.x) + v2 * bf2f(q2.x) + v3 * bf2f(q3.x);
        ay += v0 * bf2f(q0.y) + v1 * bf2f(q1.y) + v2 * bf2f(q2.y) + v3 * bf2f(q3.y);
        az += v0 * bf2f(q0.z) + v1 * bf2f(q1.z) + v2 * bf2f(q2.z) + v3 * bf2f(q3.z);
        aw += v0 * bf2f(q0.w) + v1 * bf2f(q1.w) + v2 * bf2f(q2.w) + v3 * bf2f(q3.w);
    }
    ax += __shfl_xor(ax, 16); ay += __shfl_xor(ay, 16);
    az += __shfl_xor(az, 16); aw += __shfl_xor(aw, 16);
    ax += __shfl_xor(ax, 32); ay += __shfl_xor(ay, 32);
    az += __shfl_xor(az, 32); aw += __shfl_xor(aw, 32);
    if (sub == 0) {
        ushort4 nv;
        nv.x = f2bf(ax); nv.y = f2bf(ay); nv.z = f2bf(az); nv.w = f2bf(aw);
        *(ushort4*)(next + (size_t)wave * 64 + dl * 4) = nv;
    } else if (sub == 1 && flag[wave]) {
        float* o = out_acc + (size_t)wave * 64 + dl * 4;
        float4 ov = *(const float4*)o;
        ov.x += ax; ov.y += ay; ov.z += az; ov.w += aw;
        *(float4*)o = ov;
    }
}

// ---------------------------------------------------------------------------
// Layer-2 (masked) SpMM: only rows in flist. Same batched-edge form.
// ---------------------------------------------------------------------------
__global__ __launch_bounds__(256) void spmm_masked_kernel(
    const unsigned short* __restrict__ prev, float* __restrict__ out_acc,
    const int* __restrict__ rp, const uint2* __restrict__ rec,
    unsigned long long maskbits, const int* __restrict__ flist,
    const int* __restrict__ fcount) {
    int w = (int)((blockIdx.x * (unsigned)blockDim.x + threadIdx.x) >> 6);
    int lane = threadIdx.x & 63;
    if (w >= *fcount) return;
    int sub = lane >> 4;
    int dl = lane & 15;
    int row = flist[w];
    int s = rp[row], e2 = rp[row + 1];
    float ax = 0.f, ay = 0.f, az = 0.f, aw = 0.f;
    for (int ew = s + sub; ew < e2; ew += 16) {
        int i1 = ew + 4, i2 = ew + 8, i3 = ew + 12;
        uint2 r0 = rec[ew];
        uint2 r1 = rec[i1 < e2 ? i1 : ew];
        uint2 r2 = rec[i2 < e2 ? i2 : ew];
        uint2 r3 = rec[i3 < e2 ? i3 : ew];
        float v0 = __uint_as_float(r0.y);
        float v1 = (i1 < e2) ? __uint_as_float(r1.y) : 0.f;
        float v2 = (i2 < e2) ? __uint_as_float(r2.y) : 0.f;
        float v3 = (i3 < e2) ? __uint_as_float(r3.y) : 0.f;
        ushort4 q0 = *(const ushort4*)(prev + (size_t)(r0.x & COLMASK) * 64 + dl * 4);
        ushort4 q1 = *(const ushort4*)(prev + (size_t)(r1.x & COLMASK) * 64 + dl * 4);
        ushort4 q2 = *(const ushort4*)(prev + (size_t)(r2.x & COLMASK) * 64 + dl * 4);
        ushort4 q3 = *(const ushort4*)(prev + (size_t)(r3.x & COLMASK) * 64 + dl * 4);
        ax += v0 * bf2f(q0.x) + v1 * bf2f(q1.x) + v2 * bf2f(q2.x) + v3 * bf2f(q3.x);
        ay += v0 * bf2f(q0.y) + v1 * bf2f(q1.y) + v2 * bf2f(q2.y) + v3 * bf2f(q3.y);
        az += v0 * bf2f(q0.z) + v1 * bf2f(q1.z) + v2 * bf2f(q2.z) + v3 * bf2f(q3.z);
        aw += v0 * bf2f(q0.w) + v1 * bf2f(q1.w) + v2 * bf2f(q2.w) + v3 * bf2f(q3.w);
    }
    ax += __shfl_xor(ax, 16); ay += __shfl_xor(ay, 16);
    az += __shfl_xor(az, 16); aw += __shfl_xor(aw, 16);
    ax += __shfl_xor(ax, 32); ay += __shfl_xor(ay, 32);
    az += __shfl_xor(az, 32); aw += __shfl_xor(aw, 32);
    if (sub == 0) {
        ushort4 pq = *(const ushort4*)(prev + (size_t)row * 64 + dl * 4);
        float px = bf2f(pq.x), py = bf2f(pq.y), pz = bf2f(pq.z), pw = bf2f(pq.w);
        float rx = ((maskbits >> (dl * 4 + 0)) & 1ull) ? ax : px;
        float ry = ((maskbits >> (dl * 4 + 1)) & 1ull) ? ay : py;
        float rz = ((maskbits >> (dl * 4 + 2)) & 1ull) ? az : pz;
        float rw = ((maskbits >> (dl * 4 + 3)) & 1ull) ? aw : pw;
        float* o = out_acc + (size_t)row * 64 + dl * 4;
        float4 ov = *(const float4*)o;
        ov.x += rx; ov.y += ry; ov.z += rz; ov.w += rw;
        *(float4*)o = ov;
    }
}

// ---------------------------------------------------------------------------
// Final: out[b] = (1/R^2) * dot(out_acc[users[b]], out_acc[U+items[b]])
// ---------------------------------------------------------------------------
__global__ __launch_bounds__(256) void dot_kernel(
    const float* __restrict__ out_acc, const int* __restrict__ users,
    const int* __restrict__ items, float* __restrict__ out,
    int Bn, int U, float scale) {
    int w = (int)((blockIdx.x * (unsigned)blockDim.x + threadIdx.x) >> 6);
    int lane = threadIdx.x & 63;
    if (w >= Bn) return;
    int u = users[w], it = items[w];
    float a = out_acc[(size_t)u * 64 + lane];
    float c = out_acc[((size_t)(U + it)) * 64 + lane];
    float p = a * c;
    #pragma unroll
    for (int off = 32; off > 0; off >>= 1) p += __shfl_down(p, off);
    if (lane == 0) out[w] = p * scale;
}

// ---------------------------------------------------------------------------
extern "C" void kernel_launch(void* const* d_in, const int* in_sizes, int n_in,
                              void* d_out, int out_size, void* d_ws, size_t ws_size,
                              hipStream_t stream) {
    const int* users = (const int*)d_in[0];
    const int* items = (const int*)d_in[1];
    const float* user_emb = (const float*)d_in[2];
    const float* item_emb = (const float*)d_in[3];
    const float* rating_emb = (const float*)d_in[4];
    const float* W1 = (const float*)d_in[5];
    const float* b1 = (const float*)d_in[6];
    const float* W2 = (const float*)d_in[7];
    const float* b2 = (const float*)d_in[8];
    const int* rows = (const int*)d_in[9];
    const int* cols = (const int*)d_in[10];
    const float* vals = (const float*)d_in[11];
    float* out = (float*)d_out;

    const int Dd = 64;
    int U = in_sizes[2] / Dd;
    int I = in_sizes[3] / Dd;
    int R = in_sizes[4] / Dd;
    int N = U + I;
    int E = in_sizes[9] / R;
    int Bn = in_sizes[0];
    int K = (N + NRB - 1) / NRB;    // 256-row buckets; K+1 <= 2048
    int nb = (E + EPB - 1) / EPB;   // count/scatter blocks per rating

    auto al = [](size_t b) { return (b + 255) & ~(size_t)255; };
    size_t base_need = al((size_t)N * 64 * 4) + 2 * al((size_t)N * 64 * 2)
        + al((size_t)R * K * 4)
        + al((size_t)R * (K + 1) * 4) + al((size_t)R * nb * K * 4)
        + al((size_t)R * (N + 1) * 4) + al((size_t)R * 64 * 4)
        + al((size_t)N) + al((size_t)2 * Bn * 4) + al(4);
    size_t rec_one = al((size_t)E * 8);
    size_t rec_all = al((size_t)E * 8 * R);
    // Batched build needs rec+srec for all R ratings simultaneously.
    int batched = (ws_size >= base_need + 2 * rec_all + 65536) ? 1 : 0;
    size_t recsz = batched ? rec_all : rec_one;

    char* p = (char*)d_ws;
    auto carve = [&](size_t bytes) -> char* {
        char* q = p;
        p += (bytes + 255) & ~(size_t)255;
        return q;
    };
    float* out_acc = (float*)carve((size_t)N * 64 * 4);
    unsigned short* bufA = (unsigned short*)carve((size_t)N * 64 * 2);
    unsigned short* bufB = (unsigned short*)carve((size_t)N * 64 * 2);
    uint2* rec = (uint2*)carve(recsz);
    uint2* srec = (uint2*)carve(recsz);
    int* gcnt = (int*)carve((size_t)R * K * 4);
    int* bptr = (int*)carve((size_t)R * (K + 1) * 4);
    int* blockBase = (int*)carve((size_t)R * nb * K * 4);
    int* row_ptr = (int*)carve((size_t)R * (N + 1) * 4);
    float* c1_all = (float*)carve((size_t)R * 64 * 4);
    unsigned char* flag = (unsigned char*)carve((size_t)N);
    int* flist = (int*)carve((size_t)2 * Bn * 4);
    int* fcount = (int*)carve(4);

    uint64_t maskbits = compute_mask_bits();

    hipMemsetAsync(flag, 0, (size_t)N, stream);
    hipMemsetAsync(fcount, 0, 4, stream);
    hipMemsetAsync(gcnt, 0, (size_t)R * K * 4, stream);

    flag_kernel<<<(2 * Bn + 255) / 256, 256, 0, stream>>>(users, items, flag, Bn, U);
    flist_kernel<<<(N + 255) / 256, 256, 0, stream>>>(flag, flist, fcount, N);
    c1_kernel<<<R, 64, 0, stream>>>(rating_emb, W1, b1, c1_all);

    // Build pass A (batched over ratings) + per-rating scans
    dim3 cgrid(nb, R);
    bucket_count_kernel<<<cgrid, 1024, 0, stream>>>(rows, gcnt, blockBase, E, K, nb);
    bucket_scan_kernel<<<R, 256, 0, stream>>>(gcnt, bptr, K);

    if (batched) {
        dim3 sgrid(nb, R);
        if (K <= 512)
            bucket_scatter_kernel<<<sgrid, 1024, 0, stream>>>(
                rows, cols, vals, bptr, blockBase, rec, E, K,
                (long long)E, (long long)(K + 1), (long long)nb * K, (long long)E);
        else
            bucket_scatter_legacy<<<sgrid, 1024, 0, stream>>>(
                rows, cols, vals, bptr, blockBase, rec, E, K,
                (long long)E, (long long)(K + 1), (long long)nb * K, (long long)E);
        dim3 ogrid(K, R);
        bucket_sort_kernel<<<ogrid, 256, 0, stream>>>(
            rec, srec, bptr, row_ptr, K, N,
            (long long)E, (long long)(K + 1), (long long)(N + 1));
    }

    int spmm_blocks = (N + 3) / 4;
    int masked_blocks = (2 * Bn + 3) / 4;
    for (int r = 0; r < R; r++) {
        const int* bptr_r = bptr + (size_t)r * (K + 1);
        int* rp_r = row_ptr + (size_t)r * (N + 1);
        uint2* srec_r = batched ? (srec + (size_t)r * E) : srec;

        if (!batched) {
            dim3 sgrid(nb, 1);
            if (K <= 512)
                bucket_scatter_kernel<<<sgrid, 1024, 0, stream>>>(
                    rows + (size_t)r * E, cols + (size_t)r * E, vals + (size_t)r * E,
                    bptr_r, blockBase + (size_t)r * nb * K, rec, E, K, 0, 0, 0, 0);
            else
                bucket_scatter_legacy<<<sgrid, 1024, 0, stream>>>(
                    rows + (size_t)r * E, cols + (size_t)r * E, vals + (size_t)r * E,
                    bptr_r, blockBase + (size_t)r * nb * K, rec, E, K, 0, 0, 0, 0);
            dim3 ogrid(K, 1);
            bucket_sort_kernel<<<ogrid, 256, 0, stream>>>(
                rec, srec, bptr_r, rp_r, K, N, 0, 0, 0);
        }

        mlp_kernel<<<(N + 127) / 128, 128, 0, stream>>>(user_emb, item_emb, W1, W2,
                                                        c1_all, b2, bufA, out_acc,
                                                        flag, r, N, U, (r == 0) ? 1 : 0);

        spmm_kernel<<<spmm_blocks, 256, 0, stream>>>(bufA, bufB, out_acc, rp_r,
                                                     srec_r, flag, N);
        spmm_kernel<<<spmm_blocks, 256, 0, stream>>>(bufB, bufA, out_acc, rp_r,
                                                     srec_r, flag, N);
        spmm_masked_kernel<<<masked_blocks, 256, 0, stream>>>(bufA, out_acc, rp_r,
                                                              srec_r, maskbits,
                                                              flist, fcount);
    }

    float scale = 1.0f / (float)(R * R);
    dot_kernel<<<(Bn * 64 + 255) / 256, 256, 0, stream>>>(out_acc, users, items, out,
                                                          Bn, U, scale);
}

// Round 7
// 805.341 us; speedup vs baseline: 1.0698x; 1.0698x over previous
//
#include <hip/hip_runtime.h>
#include <hip/hip_bf16.h>
#include <cstdint>
#include <cstddef>

#define KEYSHIFT 20
#define COLMASK 0xFFFFFu
#define EPB 8192    // edges per count/scatter block (1024 threads x 8)
#define SUB 4096    // staged sub-chunk inside scatter (fits 54KB LDS)
#define BSHIFT 8    // 256 rows per bucket
#define NRB 256     // rows per bucket (1 << BSHIFT)
#define CCAP 3072   // LDS sort capacity per bucket (avg ~2560, max ~2750)

// bf16 pack/unpack: gathered operand is bf16 (halves the L2-miss fill
// traffic); all accumulation stays fp32.
__device__ __forceinline__ unsigned short f2bf(float f) {
    uint32_t u = __float_as_uint(f);
    u += ((u >> 16) & 1u) + 0x7fffu;   // RNE
    return (unsigned short)(u >> 16);
}
__device__ __forceinline__ float bf2f(unsigned short h) {
    return __uint_as_float(((uint32_t)h) << 16);
}

// ---------------------------------------------------------------------------
// Host-side reproduction of np.random.RandomState(2).permutation(64):
// MT19937 init_genrand(2), Fisher-Yates with numpy random_interval
// (mask+rejection). Mask bit d = (perm[d] >= 38).
// ---------------------------------------------------------------------------
static uint64_t compute_mask_bits() {
    uint32_t mt[624];
    mt[0] = 2u;
    for (int i = 1; i < 624; i++)
        mt[i] = 1812433253u * (mt[i - 1] ^ (mt[i - 1] >> 30)) + (uint32_t)i;
    int mti = 624;
    auto genrand = [&]() -> uint32_t {
        if (mti >= 624) {
            for (int k = 0; k < 624; k++) {
                uint32_t y = (mt[k] & 0x80000000u) | (mt[(k + 1) % 624] & 0x7fffffffu);
                mt[k] = mt[(k + 397) % 624] ^ (y >> 1) ^ ((y & 1u) ? 2567483615u : 0u);
            }
            mti = 0;
        }
        uint32_t y = mt[mti++];
        y ^= y >> 11;
        y ^= (y << 7) & 2636928640u;
        y ^= (y << 15) & 4022730752u;
        y ^= y >> 18;
        return y;
    };
    int arr[64];
    for (int i = 0; i < 64; i++) arr[i] = i;
    for (int i = 63; i >= 1; i--) {
        uint32_t mask = (uint32_t)i;
        mask |= mask >> 1; mask |= mask >> 2; mask |= mask >> 4;
        mask |= mask >> 8; mask |= mask >> 16;
        uint32_t v;
        do { v = genrand() & mask; } while (v > (uint32_t)i);
        int tmp = arr[i]; arr[i] = arr[v]; arr[v] = tmp;
    }
    uint64_t bits = 0;
    for (int d = 0; d < 64; d++)
        if (arr[d] >= 38) bits |= (1ull << d);
    return bits;
}

// ---------------------------------------------------------------------------
// Output-row flag set + compacted list (rows read by the final dot).
// ---------------------------------------------------------------------------
__global__ void flag_kernel(const int* __restrict__ users, const int* __restrict__ items,
                            unsigned char* __restrict__ flag, int B, int U) {
    int i = blockIdx.x * 256 + threadIdx.x;
    if (i < B) flag[users[i]] = 1;
    else if (i < 2 * B) flag[U + items[i - B]] = 1;
}

__global__ void flist_kernel(const unsigned char* __restrict__ flag,
                             int* __restrict__ flist, int* __restrict__ fcount, int n) {
    int i = blockIdx.x * 256 + threadIdx.x;
    if (i < n && flag[i]) {
        int p = atomicAdd(fcount, 1);
        flist[p] = i;
    }
}

// ---------------------------------------------------------------------------
// Per-rating constant c1[r][j] = b1[r][j] + sum_k e_r[k] * W1[r][64+k][j].
// ---------------------------------------------------------------------------
__global__ void c1_kernel(const float* __restrict__ rating_emb, const float* __restrict__ W1,
                          const float* __restrict__ b1, float* __restrict__ c1_all) {
    int r = blockIdx.x;
    int t = threadIdx.x;  // 64 threads
    const float* W1r = W1 + (size_t)r * (128 * 64);
    float acc = b1[r * 64 + t];
    for (int k = 0; k < 64; k++)
        acc += rating_emb[r * 64 + k] * W1r[(64 + k) * 64 + t];
    c1_all[r * 64 + t] = acc;
}

// ---------------------------------------------------------------------------
// Build pass A (batched over ratings): LDS histogram over K=ceil(N/256) row
// buckets, then ONE global atomicAdd per (block,bucket) to reserve a range.
// ---------------------------------------------------------------------------
__global__ __launch_bounds__(1024) void bucket_count_kernel(
    const int* __restrict__ rows, int* __restrict__ gcnt,
    int* __restrict__ blockBase, int E, int K, int nb) {
    __shared__ int hist[2048];
    int r = blockIdx.y, blk = blockIdx.x, t = threadIdx.x;
    for (int i = t; i < K; i += 1024) hist[i] = 0;
    __syncthreads();
    size_t base = (size_t)r * E + (size_t)blk * EPB;
    int cnt = E - blk * EPB;
    if (cnt > EPB) cnt = EPB;
    for (int k = t; k < cnt; k += 1024)
        atomicAdd(&hist[rows[base + k] >> BSHIFT], 1);
    __syncthreads();
    for (int i = t; i < K; i += 1024) {
        int c = hist[i];
        int bb = (c > 0) ? atomicAdd(&gcnt[r * K + i], c) : 0;
        blockBase[((size_t)r * nb + blk) * K + i] = bb;
    }
}

// ---------------------------------------------------------------------------
// Exclusive scan of K bucket counts -> bptr[K+1] per rating (grid.x = R).
// ---------------------------------------------------------------------------
__global__ void bucket_scan_kernel(const int* __restrict__ gcnt,
                                   int* __restrict__ bptr, int K) {
    __shared__ int sh[256];
    int r = blockIdx.x;
    int t = threadIdx.x;
    int base = t * 8;
    int v[8];
    int s = 0;
    #pragma unroll
    for (int j = 0; j < 8; j++) {
        int idx = base + j;
        v[j] = (idx < K) ? gcnt[r * K + idx] : 0;
        s += v[j];
    }
    sh[t] = s;
    __syncthreads();
    for (int off = 1; off < 256; off <<= 1) {
        int x = (t >= off) ? sh[t - off] : 0;
        __syncthreads();
        sh[t] += x;
        __syncthreads();
    }
    int run = sh[t] - s;
    #pragma unroll
    for (int j = 0; j < 8; j++) {
        int idx = base + j;
        if (idx <= K) bptr[r * (K + 1) + idx] = run;
        run += v[j];
    }
}

// ---------------------------------------------------------------------------
// Build pass B: LDS-STAGED scatter into bucket-grouped rec (K <= 512).
// Each 4096-edge sub-chunk is histogrammed, scanned, staged bucket-grouped
// in LDS with its final global address, then written out linearly.
// ---------------------------------------------------------------------------
__global__ __launch_bounds__(1024) void bucket_scatter_kernel(
    const int* __restrict__ rows, const int* __restrict__ cols,
    const float* __restrict__ vals, const int* __restrict__ bptr,
    const int* __restrict__ blockBase, uint2* __restrict__ rec,
    int E, int K, long long eStride, long long pStride,
    long long bbStride, long long rStride) {
    __shared__ uint2 staged[SUB];   // 32KB
    __shared__ int gaddr[SUB];      // 16KB final rec index per staged slot
    __shared__ int cursor[512];     // running global cursor per bucket
    __shared__ int lhist[512];      // per-subchunk count -> local base
    __shared__ int aux[512];        // scan scratch -> goff (=gbase-localbase)
    int r = blockIdx.y;
    const int* rows_r = rows + (size_t)r * eStride;
    const int* cols_r = cols + (size_t)r * eStride;
    const float* vals_r = vals + (size_t)r * eStride;
    const int* bptr_r = bptr + (size_t)r * pStride;
    const int* bb_r = blockBase + (size_t)r * bbStride;
    uint2* rec_r = rec + (size_t)r * rStride;
    int blk = blockIdx.x, t = threadIdx.x;
    if (t < 512)
        cursor[t] = (t < K) ? (bptr_r[t] + bb_r[(size_t)blk * K + t]) : 0;
    size_t base = (size_t)blk * EPB;
    int cnt = E - blk * EPB;
    if (cnt > EPB) cnt = EPB;
    for (int c0 = 0; c0 < cnt; c0 += SUB) {
        int scnt = cnt - c0;
        if (scnt > SUB) scnt = SUB;
        if (t < 512) lhist[t] = 0;
        __syncthreads();
        int bkt_[4], lpos_[4];
        uint2 rv_[4];
        #pragma unroll
        for (int q = 0; q < 4; q++) {
            int kk = (q << 10) + t;
            bkt_[q] = -1;
            if (kk < scnt) {
                size_t g = base + c0 + kk;
                int row = rows_r[g];
                int b = row >> BSHIFT;
                bkt_[q] = b;
                rv_[q] = make_uint2(((uint32_t)(row & (NRB - 1)) << KEYSHIFT) |
                                        (uint32_t)cols_r[g],
                                    __float_as_uint(vals_r[g]));
                lpos_[q] = atomicAdd(&lhist[b], 1);
            }
        }
        __syncthreads();
        int v = (t < 512) ? lhist[t] : 0;
        if (t < 512) aux[t] = v;
        __syncthreads();
        for (int off = 1; off < 512; off <<= 1) {
            int x = 0;
            if (t >= off && t < 512) x = aux[t - off];
            __syncthreads();
            if (t < 512) aux[t] += x;
            __syncthreads();
        }
        if (t < 512) {
            int ex = aux[t] - v;     // exclusive local base
            int gb = cursor[t];      // global base for this sub-chunk
            cursor[t] = gb + v;
            lhist[t] = ex;
            aux[t] = gb - ex;        // goff: gaddr = goff[b] + staged_idx
        }
        __syncthreads();
        #pragma unroll
        for (int q = 0; q < 4; q++) {
            if (bkt_[q] >= 0) {
                int sidx = lhist[bkt_[q]] + lpos_[q];
                staged[sidx] = rv_[q];
                gaddr[sidx] = aux[bkt_[q]] + sidx;
            }
        }
        __syncthreads();
        for (int i = t; i < scnt; i += 1024)
            rec_r[gaddr[i]] = staged[i];
        __syncthreads();
    }
}

// ---------------------------------------------------------------------------
// Build pass B legacy (direct scatter) — only used if K > 512.
// ---------------------------------------------------------------------------
__global__ __launch_bounds__(1024) void bucket_scatter_legacy(
    const int* __restrict__ rows, const int* __restrict__ cols,
    const float* __restrict__ vals, const int* __restrict__ bptr,
    const int* __restrict__ blockBase, uint2* __restrict__ rec,
    int E, int K, long long eStride, long long pStride,
    long long bbStride, long long rStride) {
    __shared__ int cursor[2048];
    int r = blockIdx.y;
    const int* rows_r = rows + (size_t)r * eStride;
    const int* cols_r = cols + (size_t)r * eStride;
    const float* vals_r = vals + (size_t)r * eStride;
    const int* bptr_r = bptr + (size_t)r * pStride;
    const int* bb_r = blockBase + (size_t)r * bbStride;
    uint2* rec_r = rec + (size_t)r * rStride;
    int blk = blockIdx.x, t = threadIdx.x;
    for (int i = t; i < K; i += 1024)
        cursor[i] = bptr_r[i] + bb_r[(size_t)blk * K + i];
    __syncthreads();
    size_t base = (size_t)blk * EPB;
    int cnt = E - blk * EPB;
    if (cnt > EPB) cnt = EPB;
    for (int k = t; k < cnt; k += 1024) {
        int row = rows_r[base + k];
        int b = row >> BSHIFT;
        int pos = atomicAdd(&cursor[b], 1);
        uint32_t key = ((uint32_t)(row & (NRB - 1)) << KEYSHIFT) | (uint32_t)cols_r[base + k];
        rec_r[pos] = make_uint2(key, __float_as_uint(vals_r[base + k]));
    }
}

// ---------------------------------------------------------------------------
// Build pass C: per-bucket counting sort by rel-row, FULLY IN LDS; srec
// written as one dense coalesced stream. Emits row_ptr.
// ---------------------------------------------------------------------------
__global__ __launch_bounds__(256) void bucket_sort_kernel(
    const uint2* __restrict__ rec, uint2* __restrict__ srec,
    const int* __restrict__ bptr, int* __restrict__ rp, int K, int N,
    long long rStride, long long pStride, long long rpStride) {
    __shared__ uint2 staged[CCAP];  // 24KB
    __shared__ int hist[NRB];
    __shared__ int excl[NRB];
    int r = blockIdx.y;
    const uint2* rec_r = rec + (size_t)r * rStride;
    uint2* srec_r = srec + (size_t)r * rStride;
    const int* bptr_r = bptr + (size_t)r * pStride;
    int* rp_r = rp + (size_t)r * rpStride;
    int b = blockIdx.x;
    int t = threadIdx.x;          // 256 threads == NRB
    hist[t] = 0;
    __syncthreads();
    int start = bptr_r[b], end = bptr_r[b + 1];
    int m = end - start;
    for (int e = start + t; e < end; e += 256)
        atomicAdd(&hist[rec_r[e].x >> KEYSHIFT], 1);
    __syncthreads();
    int v = hist[t];
    excl[t] = v;
    __syncthreads();
    for (int off = 1; off < 256; off <<= 1) {
        int x = (t >= off) ? excl[t - off] : 0;
        __syncthreads();
        excl[t] += x;
        __syncthreads();
    }
    int ex = excl[t] - v;
    excl[t] = ex;                 // own-slot overwrite, no cross-read yet
    hist[t] = 0;                  // reuse as cursors
    int row = b * NRB + t;
    if (row < N) rp_r[row] = start + ex;
    if (b == K - 1 && t == 0) rp_r[N] = bptr_r[K];
    __syncthreads();
    if (m <= CCAP) {
        for (int e = start + t; e < end; e += 256) {
            uint2 rr = rec_r[e];
            int rel = (int)(rr.x >> KEYSHIFT);
            int pos = excl[rel] + atomicAdd(&hist[rel], 1);
            staged[pos] = rr;
        }
        __syncthreads();
        for (int i = t; i < m; i += 256)
            srec_r[start + i] = staged[i];
    } else {
        for (int e = start + t; e < end; e += 256) {
            uint2 rr = rec_r[e];
            int rel = (int)(rr.x >> KEYSHIFT);
            int pos = start + excl[rel] + atomicAdd(&hist[rel], 1);
            srec_r[pos] = rr;
        }
    }
}

// ---------------------------------------------------------------------------
// Per-rating MLP: h = leaky_relu(x @ W1a + c1) @ W2 + b2
// R18 restructure after two failed mlp rounds (R5 occupancy-null, R6
// occupancy-collapse): W never touches LDS/VALU paths. lane=row (64 rows
// per 256-thr block), wave=16-col slice with readfirstlane'd jbase so all
// W/c1/b2 accesses are SCALAR (SMEM) loads on the scalar pipe. X staged
// once in a pad-68 LDS tile (17.7KB): per GEMM a lane does 16 ds_read_b128
// (own row, even 8-bank-group spread = b128 baseline) + 1024 FMAs. LDS
// instrs/thread 256 -> 40; 6-8 waves/SIMD hide latency. fp32 throughout.
// ---------------------------------------------------------------------------
__global__ __launch_bounds__(256, 4) void mlp_kernel(
    const float* __restrict__ user_emb, const float* __restrict__ item_emb,
    const float* __restrict__ W1, const float* __restrict__ W2,
    const float* __restrict__ c1_all, const float* __restrict__ b2,
    unsigned short* __restrict__ prev, float* __restrict__ out_acc,
    const unsigned char* __restrict__ flag, int r, int n_rows, int U, int init) {
    __shared__ float sX[64 * 68];   // 64 rows, pad-68 (17.4KB); X then T

    int t = threadIdx.x;
    int lane = t & 63;
    int row0 = blockIdx.x * 64;
    int jbase = __builtin_amdgcn_readfirstlane((t >> 6) << 4);  // 0/16/32/48
    const float* W1r = W1 + (size_t)r * (128 * 64);
    const float* W2r = W2 + (size_t)r * (64 * 64);

    // Stage X: 1024 float4 / 256 threads = 4 each, coalesced global reads.
    #pragma unroll
    for (int q = 0; q < 4; q++) {
        int f = t + 256 * q;
        int i = f >> 4, c = (f & 15) * 4;
        int nrow = row0 + i;
        float4 xv = make_float4(0.f, 0.f, 0.f, 0.f);
        if (nrow < n_rows) {
            const float* src = (nrow < U) ? (user_emb + (size_t)nrow * 64)
                                          : (item_emb + (size_t)(nrow - U) * 64);
            xv = *(const float4*)(src + c);
        }
        *(float4*)(sX + i * 68 + c) = xv;
    }
    __syncthreads();

    // acc = c1[jbase..jbase+15] (uniform scalar loads)
    const float* c1p = c1_all + r * 64 + jbase;
    float4 a0 = *(const float4*)(c1p + 0);
    float4 a1 = *(const float4*)(c1p + 4);
    float4 a2 = *(const float4*)(c1p + 8);
    float4 a3 = *(const float4*)(c1p + 12);

    // GEMM1: row=lane, cols jbase..+15; X from LDS, W scalar-streamed.
    #pragma unroll
    for (int m = 0; m < 16; m++) {
        float4 xv = *(const float4*)(sX + lane * 68 + 4 * m);
        const float* wk = W1r + (4 * m) * 64 + jbase;
        #pragma unroll
        for (int kk = 0; kk < 4; kk++) {
            float xs = (kk == 0) ? xv.x : (kk == 1) ? xv.y : (kk == 2) ? xv.z : xv.w;
            float4 w0 = *(const float4*)(wk + kk * 64 + 0);
            float4 w1 = *(const float4*)(wk + kk * 64 + 4);
            float4 w2 = *(const float4*)(wk + kk * 64 + 8);
            float4 w3 = *(const float4*)(wk + kk * 64 + 12);
            a0.x += xs * w0.x; a0.y += xs * w0.y; a0.z += xs * w0.z; a0.w += xs * w0.w;
            a1.x += xs * w1.x; a1.y += xs * w1.y; a1.z += xs * w1.z; a1.w += xs * w1.w;
            a2.x += xs * w2.x; a2.y += xs * w2.y; a2.z += xs * w2.z; a2.w += xs * w2.w;
            a3.x += xs * w3.x; a3.y += xs * w3.y; a3.z += xs * w3.z; a3.w += xs * w3.w;
        }
    }
    // leaky_relu
    a0.x = (a0.x >= 0.f) ? a0.x : 0.01f * a0.x;
    a0.y = (a0.y >= 0.f) ? a0.y : 0.01f * a0.y;
    a0.z = (a0.z >= 0.f) ? a0.z : 0.01f * a0.z;
    a0.w = (a0.w >= 0.f) ? a0.w : 0.01f * a0.w;
    a1.x = (a1.x >= 0.f) ? a1.x : 0.01f * a1.x;
    a1.y = (a1.y >= 0.f) ? a1.y : 0.01f * a1.y;
    a1.z = (a1.z >= 0.f) ? a1.z : 0.01f * a1.z;
    a1.w = (a1.w >= 0.f) ? a1.w : 0.01f * a1.w;
    a2.x = (a2.x >= 0.f) ? a2.x : 0.01f * a2.x;
    a2.y = (a2.y >= 0.f) ? a2.y : 0.01f * a2.y;
    a2.z = (a2.z >= 0.f) ? a2.z : 0.01f * a2.z;
    a2.w = (a2.w >= 0.f) ? a2.w : 0.01f * a2.w;
    a3.x = (a3.x >= 0.f) ? a3.x : 0.01f * a3.x;
    a3.y = (a3.y >= 0.f) ? a3.y : 0.01f * a3.y;
    a3.z = (a3.z >= 0.f) ? a3.z : 0.01f * a3.z;
    a3.w = (a3.w >= 0.f) ? a3.w : 0.01f * a3.w;

    __syncthreads();   // all GEMM1 reads of sX complete before T overwrites
    *(float4*)(sX + lane * 68 + jbase + 0) = a0;
    *(float4*)(sX + lane * 68 + jbase + 4) = a1;
    *(float4*)(sX + lane * 68 + jbase + 8) = a2;
    *(float4*)(sX + lane * 68 + jbase + 12) = a3;
    __syncthreads();

    // acc = b2[jbase..+15]
    const float* b2p = b2 + r * 64 + jbase;
    a0 = *(const float4*)(b2p + 0);
    a1 = *(const float4*)(b2p + 4);
    a2 = *(const float4*)(b2p + 8);
    a3 = *(const float4*)(b2p + 12);

    // GEMM2: T from LDS, W2 scalar-streamed.
    #pragma unroll
    for (int m = 0; m < 16; m++) {
        float4 xv = *(const float4*)(sX + lane * 68 + 4 * m);
        const float* wk = W2r + (4 * m) * 64 + jbase;
        #pragma unroll
        for (int kk = 0; kk < 4; kk++) {
            float xs = (kk == 0) ? xv.x : (kk == 1) ? xv.y : (kk == 2) ? xv.z : xv.w;
            float4 w0 = *(const float4*)(wk + kk * 64 + 0);
            float4 w1 = *(const float4*)(wk + kk * 64 + 4);
            float4 w2 = *(const float4*)(wk + kk * 64 + 8);
            float4 w3 = *(const float4*)(wk + kk * 64 + 12);
            a0.x += xs * w0.x; a0.y += xs * w0.y; a0.z += xs * w0.z; a0.w += xs * w0.w;
            a1.x += xs * w1.x; a1.y += xs * w1.y; a1.z += xs * w1.z; a1.w += xs * w1.w;
            a2.x += xs * w2.x; a2.y += xs * w2.y; a2.z += xs * w2.z; a2.w += xs * w2.w;
            a3.x += xs * w3.x; a3.y += xs * w3.y; a3.z += xs * w3.z; a3.w += xs * w3.w;
        }
    }

    // Epilogue: lane writes row (row0+lane), cols jbase..+15.
    int nrow = row0 + lane;
    if (nrow < n_rows) {
        unsigned short* pp = prev + (size_t)nrow * 64 + jbase;
        ushort4 h0, h1, h2, h3;
        h0.x = f2bf(a0.x); h0.y = f2bf(a0.y); h0.z = f2bf(a0.z); h0.w = f2bf(a0.w);
        h1.x = f2bf(a1.x); h1.y = f2bf(a1.y); h1.z = f2bf(a1.z); h1.w = f2bf(a1.w);
        h2.x = f2bf(a2.x); h2.y = f2bf(a2.y); h2.z = f2bf(a2.z); h2.w = f2bf(a2.w);
        h3.x = f2bf(a3.x); h3.y = f2bf(a3.y); h3.z = f2bf(a3.z); h3.w = f2bf(a3.w);
        *(ushort4*)(pp + 0) = h0;
        *(ushort4*)(pp + 4) = h1;
        *(ushort4*)(pp + 8) = h2;
        *(ushort4*)(pp + 12) = h3;
        if (flag[nrow]) {
            float* o = out_acc + (size_t)nrow * 64 + jbase;
            if (init) {
                *(float4*)(o + 0) = a0;
                *(float4*)(o + 4) = a1;
                *(float4*)(o + 8) = a2;
                *(float4*)(o + 12) = a3;
            } else {
                float4 o0 = *(const float4*)(o + 0);
                float4 o1 = *(const float4*)(o + 4);
                float4 o2 = *(const float4*)(o + 8);
                float4 o3 = *(const float4*)(o + 12);
                o0.x += a0.x; o0.y += a0.y; o0.z += a0.z; o0.w += a0.w;
                o1.x += a1.x; o1.y += a1.y; o1.z += a1.z; o1.w += a1.w;
                o2.x += a2.x; o2.y += a2.y; o2.z += a2.z; o2.w += a2.w;
                o3.x += a3.x; o3.y += a3.y; o3.z += a3.z; o3.w += a3.w;
                *(float4*)(o + 0) = o0;
                *(float4*)(o + 4) = o1;
                *(float4*)(o + 8) = o2;
                *(float4*)(o + 12) = o3;
            }
        }
    }
}

// ---------------------------------------------------------------------------
// Gather-SpMM (layers 0/1): wave = 1 row; 4 edge-groups x 16 lanes.
// Batched 4-edge window (ILP): 4 rec loads back-to-back, then 4 gathers —
// two dependent memory legs per row. Invalid slots clamp to rec[ew] (L1
// hit) with v=0. Deg~10 -> one 16-edge window covers ~97% of rows.
// ---------------------------------------------------------------------------
__global__ __launch_bounds__(256) void spmm_kernel(
    const unsigned short* __restrict__ prev, unsigned short* __restrict__ next,
    float* __restrict__ out_acc, const int* __restrict__ rp,
    const uint2* __restrict__ rec, const unsigned char* __restrict__ flag, int n) {
    int wave = (int)((blockIdx.x * (unsigned)blockDim.x + threadIdx.x) >> 6);
    int lane = threadIdx.x & 63;
    if (wave >= n) return;
    int sub = lane >> 4;      // edge group 0..3
    int dl = lane & 15;       // dims [dl*4, dl*4+4)
    int s = rp[wave], e2 = rp[wave + 1];
    float ax = 0.f, ay = 0.f, az = 0.f, aw = 0.f;
    for (int ew = s + sub; ew < e2; ew += 16) {
        int i1 = ew + 4, i2 = ew + 8, i3 = ew + 12;
        uint2 r0 = rec[ew];
        uint2 r1 = rec[i1 < e2 ? i1 : ew];
        uint2 r2 = rec[i2 < e2 ? i2 : ew];
        uint2 r3 = rec[i3 < e2 ? i3 : ew];
        float v0 = __uint_as_float(r0.y);
        float v1 = (i1 < e2) ? __uint_as_float(r1.y) : 0.f;
        float v2 = (i2 < e2) ? __uint_as_float(r2.y) : 0.f;
        float v3 = (i3 < e2) ? __uint_as_float(r3.y) : 0.f;
        ushort4 q0 = *(const ushort4*)(prev + (size_t)(r0.x & COLMASK) * 64 + dl * 4);
        ushort4 q1 = *(const ushort4*)(prev + (size_t)(r1.x & COLMASK) * 64 + dl * 4);
        ushort4 q2 = *(const ushort4*)(prev + (size_t)(r2.x & COLMASK) * 64 + dl * 4);
        ushort4 q3 = *(const ushort4*)(prev + (size_t)(r3.x & COLMASK) * 64 + dl * 4);
        ax += v0 * bf2f(q0.x) + v1 * bf2f(q1.x) + v2 * bf2f(q2.x) + v3 * bf2f(q3.x);
        ay += v0 * bf2f(q0.y) + v1 * bf2f(q1.y) + v2 * bf2f(q2.y) + v3 * bf2f(q3.y);
        az += v0 * bf2f(q0.z) + v1 * bf2f(q1.z) + v2 * bf2f(q2.z) + v3 * bf2f(q3.z);
        aw += v0 * bf2f(q0.w) + v1 * bf2f(q1.w) + v2 * bf2f(q2.w) + v3 * bf2f(q3.w);
    }
    ax += __shfl_xor(ax, 16); ay += __shfl_xor(ay, 16);
    az += __shfl_xor(az, 16); aw += __shfl_xor(aw, 16);
    ax += __shfl_xor(ax, 32); ay += __shfl_xor(ay, 32);
    az += __shfl_xor(az, 32); aw += __shfl_xor(aw, 32);
    if (sub == 0) {
        ushort4 nv;
        nv.x = f2bf(ax); nv.y = f2bf(ay); nv.z = f2bf(az); nv.w = f2bf(aw);
        *(ushort4*)(next + (size_t)wave * 64 + dl * 4) = nv;
    } else if (sub == 1 && flag[wave]) {
        float* o = out_acc + (size_t)wave * 64 + dl * 4;
        float4 ov = *(const float4*)o;
        ov.x += ax; ov.y += ay; ov.z += az; ov.w += aw;
        *(float4*)o = ov;
    }
}

// ---------------------------------------------------------------------------
// Layer-2 (masked) SpMM: only rows in flist. Same batched-edge form.
// ---------------------------------------------------------------------------
__global__ __launch_bounds__(256) void spmm_masked_kernel(
    const unsigned short* __restrict__ prev, float* __restrict__ out_acc,
    const int* __restrict__ rp, const uint2* __restrict__ rec,
    unsigned long long maskbits, const int* __restrict__ flist,
    const int* __restrict__ fcount) {
    int w = (int)((blockIdx.x * (unsigned)blockDim.x + threadIdx.x) >> 6);
    int lane = threadIdx.x & 63;
    if (w >= *fcount) return;
    int sub = lane >> 4;
    int dl = lane & 15;
    int row = flist[w];
    int s = rp[row], e2 = rp[row + 1];
    float ax = 0.f, ay = 0.f, az = 0.f, aw = 0.f;
    for (int ew = s + sub; ew < e2; ew += 16) {
        int i1 = ew + 4, i2 = ew + 8, i3 = ew + 12;
        uint2 r0 = rec[ew];
        uint2 r1 = rec[i1 < e2 ? i1 : ew];
        uint2 r2 = rec[i2 < e2 ? i2 : ew];
        uint2 r3 = rec[i3 < e2 ? i3 : ew];
        float v0 = __uint_as_float(r0.y);
        float v1 = (i1 < e2) ? __uint_as_float(r1.y) : 0.f;
        float v2 = (i2 < e2) ? __uint_as_float(r2.y) : 0.f;
        float v3 = (i3 < e2) ? __uint_as_float(r3.y) : 0.f;
        ushort4 q0 = *(const ushort4*)(prev + (size_t)(r0.x & COLMASK) * 64 + dl * 4);
        ushort4 q1 = *(const ushort4*)(prev + (size_t)(r1.x & COLMASK) * 64 + dl * 4);
        ushort4 q2 = *(const ushort4*)(prev + (size_t)(r2.x & COLMASK) * 64 + dl * 4);
        ushort4 q3 = *(const ushort4*)(prev + (size_t)(r3.x & COLMASK) * 64 + dl * 4);
        ax += v0 * bf2f(q0.x) + v1 * bf2f(q1.x) + v2 * bf2f(q2.x) + v3 * bf2f(q3.x);
        ay += v0 * bf2f(q0.y) + v1 * bf2f(q1.y) + v2 * bf2f(q2.y) + v3 * bf2f(q3.y);
        az += v0 * bf2f(q0.z) + v1 * bf2f(q1.z) + v2 * bf2f(q2.z) + v3 * bf2f(q3.z);
        aw += v0 * bf2f(q0.w) + v1 * bf2f(q1.w) + v2 * bf2f(q2.w) + v3 * bf2f(q3.w);
    }
    ax += __shfl_xor(ax, 16); ay += __shfl_xor(ay, 16);
    az += __shfl_xor(az, 16); aw += __shfl_xor(aw, 16);
    ax += __shfl_xor(ax, 32); ay += __shfl_xor(ay, 32);
    az += __shfl_xor(az, 32); aw += __shfl_xor(aw, 32);
    if (sub == 0) {
        ushort4 pq = *(const ushort4*)(prev + (size_t)row * 64 + dl * 4);
        float px = bf2f(pq.x), py = bf2f(pq.y), pz = bf2f(pq.z), pw = bf2f(pq.w);
        float rx = ((maskbits >> (dl * 4 + 0)) & 1ull) ? ax : px;
        float ry = ((maskbits >> (dl * 4 + 1)) & 1ull) ? ay : py;
        float rz = ((maskbits >> (dl * 4 + 2)) & 1ull) ? az : pz;
        float rw = ((maskbits >> (dl * 4 + 3)) & 1ull) ? aw : pw;
        float* o = out_acc + (size_t)row * 64 + dl * 4;
        float4 ov = *(const float4*)o;
        ov.x += rx; ov.y += ry; ov.z += rz; ov.w += rw;
        *(float4*)o = ov;
    }
}

// ---------------------------------------------------------------------------
// Final: out[b] = (1/R^2) * dot(out_acc[users[b]], out_acc[U+items[b]])
// ---------------------------------------------------------------------------
__global__ __launch_bounds__(256) void dot_kernel(
    const float* __restrict__ out_acc, const int* __restrict__ users,
    const int* __restrict__ items, float* __restrict__ out,
    int Bn, int U, float scale) {
    int w = (int)((blockIdx.x * (unsigned)blockDim.x + threadIdx.x) >> 6);
    int lane = threadIdx.x & 63;
    if (w >= Bn) return;
    int u = users[w], it = items[w];
    float a = out_acc[(size_t)u * 64 + lane];
    float c = out_acc[((size_t)(U + it)) * 64 + lane];
    float p = a * c;
    #pragma unroll
    for (int off = 32; off > 0; off >>= 1) p += __shfl_down(p, off);
    if (lane == 0) out[w] = p * scale;
}

// ---------------------------------------------------------------------------
extern "C" void kernel_launch(void* const* d_in, const int* in_sizes, int n_in,
                              void* d_out, int out_size, void* d_ws, size_t ws_size,
                              hipStream_t stream) {
    const int* users = (const int*)d_in[0];
    const int* items = (const int*)d_in[1];
    const float* user_emb = (const float*)d_in[2];
    const float* item_emb = (const float*)d_in[3];
    const float* rating_emb = (const float*)d_in[4];
    const float* W1 = (const float*)d_in[5];
    const float* b1 = (const float*)d_in[6];
    const float* W2 = (const float*)d_in[7];
    const float* b2 = (const float*)d_in[8];
    const int* rows = (const int*)d_in[9];
    const int* cols = (const int*)d_in[10];
    const float* vals = (const float*)d_in[11];
    float* out = (float*)d_out;

    const int Dd = 64;
    int U = in_sizes[2] / Dd;
    int I = in_sizes[3] / Dd;
    int R = in_sizes[4] / Dd;
    int N = U + I;
    int E = in_sizes[9] / R;
    int Bn = in_sizes[0];
    int K = (N + NRB - 1) / NRB;    // 256-row buckets; K+1 <= 2048
    int nb = (E + EPB - 1) / EPB;   // count/scatter blocks per rating

    auto al = [](size_t b) { return (b + 255) & ~(size_t)255; };
    size_t base_need = al((size_t)N * 64 * 4) + 2 * al((size_t)N * 64 * 2)
        + al((size_t)R * K * 4)
        + al((size_t)R * (K + 1) * 4) + al((size_t)R * nb * K * 4)
        + al((size_t)R * (N + 1) * 4) + al((size_t)R * 64 * 4)
        + al((size_t)N) + al((size_t)2 * Bn * 4) + al(4);
    size_t rec_one = al((size_t)E * 8);
    size_t rec_all = al((size_t)E * 8 * R);
    // Batched build needs rec+srec for all R ratings simultaneously.
    int batched = (ws_size >= base_need + 2 * rec_all + 65536) ? 1 : 0;
    size_t recsz = batched ? rec_all : rec_one;

    char* p = (char*)d_ws;
    auto carve = [&](size_t bytes) -> char* {
        char* q = p;
        p += (bytes + 255) & ~(size_t)255;
        return q;
    };
    float* out_acc = (float*)carve((size_t)N * 64 * 4);
    unsigned short* bufA = (unsigned short*)carve((size_t)N * 64 * 2);
    unsigned short* bufB = (unsigned short*)carve((size_t)N * 64 * 2);
    uint2* rec = (uint2*)carve(recsz);
    uint2* srec = (uint2*)carve(recsz);
    int* gcnt = (int*)carve((size_t)R * K * 4);
    int* bptr = (int*)carve((size_t)R * (K + 1) * 4);
    int* blockBase = (int*)carve((size_t)R * nb * K * 4);
    int* row_ptr = (int*)carve((size_t)R * (N + 1) * 4);
    float* c1_all = (float*)carve((size_t)R * 64 * 4);
    unsigned char* flag = (unsigned char*)carve((size_t)N);
    int* flist = (int*)carve((size_t)2 * Bn * 4);
    int* fcount = (int*)carve(4);

    uint64_t maskbits = compute_mask_bits();

    hipMemsetAsync(flag, 0, (size_t)N, stream);
    hipMemsetAsync(fcount, 0, 4, stream);
    hipMemsetAsync(gcnt, 0, (size_t)R * K * 4, stream);

    flag_kernel<<<(2 * Bn + 255) / 256, 256, 0, stream>>>(users, items, flag, Bn, U);
    flist_kernel<<<(N + 255) / 256, 256, 0, stream>>>(flag, flist, fcount, N);
    c1_kernel<<<R, 64, 0, stream>>>(rating_emb, W1, b1, c1_all);

    // Build pass A (batched over ratings) + per-rating scans
    dim3 cgrid(nb, R);
    bucket_count_kernel<<<cgrid, 1024, 0, stream>>>(rows, gcnt, blockBase, E, K, nb);
    bucket_scan_kernel<<<R, 256, 0, stream>>>(gcnt, bptr, K);

    if (batched) {
        dim3 sgrid(nb, R);
        if (K <= 512)
            bucket_scatter_kernel<<<sgrid, 1024, 0, stream>>>(
                rows, cols, vals, bptr, blockBase, rec, E, K,
                (long long)E, (long long)(K + 1), (long long)nb * K, (long long)E);
        else
            bucket_scatter_legacy<<<sgrid, 1024, 0, stream>>>(
                rows, cols, vals, bptr, blockBase, rec, E, K,
                (long long)E, (long long)(K + 1), (long long)nb * K, (long long)E);
        dim3 ogrid(K, R);
        bucket_sort_kernel<<<ogrid, 256, 0, stream>>>(
            rec, srec, bptr, row_ptr, K, N,
            (long long)E, (long long)(K + 1), (long long)(N + 1));
    }

    int spmm_blocks = (N + 3) / 4;
    int masked_blocks = (2 * Bn + 3) / 4;
    for (int r = 0; r < R; r++) {
        const int* bptr_r = bptr + (size_t)r * (K + 1);
        int* rp_r = row_ptr + (size_t)r * (N + 1);
        uint2* srec_r = batched ? (srec + (size_t)r * E) : srec;

        if (!batched) {
            dim3 sgrid(nb, 1);
            if (K <= 512)
                bucket_scatter_kernel<<<sgrid, 1024, 0, stream>>>(
                    rows + (size_t)r * E, cols + (size_t)r * E, vals + (size_t)r * E,
                    bptr_r, blockBase + (size_t)r * nb * K, rec, E, K, 0, 0, 0, 0);
            else
                bucket_scatter_legacy<<<sgrid, 1024, 0, stream>>>(
                    rows + (size_t)r * E, cols + (size_t)r * E, vals + (size_t)r * E,
                    bptr_r, blockBase + (size_t)r * nb * K, rec, E, K, 0, 0, 0, 0);
            dim3 ogrid(K, 1);
            bucket_sort_kernel<<<ogrid, 256, 0, stream>>>(
                rec, srec, bptr_r, rp_r, K, N, 0, 0, 0);
        }

        mlp_kernel<<<(N + 63) / 64, 256, 0, stream>>>(user_emb, item_emb, W1, W2,
                                                      c1_all, b2, bufA, out_acc,
                                                      flag, r, N, U, (r == 0) ? 1 : 0);

        spmm_kernel<<<spmm_blocks, 256, 0, stream>>>(bufA, bufB, out_acc, rp_r,
                                                     srec_r, flag, N);
        spmm_kernel<<<spmm_blocks, 256, 0, stream>>>(bufB, bufA, out_acc, rp_r,
                                                     srec_r, flag, N);
        spmm_masked_kernel<<<masked_blocks, 256, 0, stream>>>(bufA, out_acc, rp_r,
                                                              srec_r, maskbits,
                                                              flist, fcount);
    }

    float scale = 1.0f / (float)(R * R);
    dot_kernel<<<(Bn * 64 + 255) / 256, 256, 0, stream>>>(out_acc, users, items, out,
                                                          Bn, U, scale);
}

// Round 8
// 764.063 us; speedup vs baseline: 1.1276x; 1.0540x over previous
//
#include <hip/hip_runtime.h>
#include <hip/hip_bf16.h>
#include <cstdint>
#include <cstddef>

#define KEYSHIFT 20
#define COLMASK 0xFFFFFu
#define EPB 8192    // edges per count/scatter block (1024 threads x 8)
#define SUB 4096    // staged sub-chunk inside scatter (fits 54KB LDS)
#define BSHIFT 8    // 256 rows per bucket
#define NRB 256     // rows per bucket (1 << BSHIFT)
#define CCAP 3072   // LDS sort capacity per bucket (avg ~2560, max ~2750)

// bf16 pack/unpack: gathered operand is bf16; accumulation fp32.
__device__ __forceinline__ unsigned short f2bf(float f) {
    uint32_t u = __float_as_uint(f);
    u += ((u >> 16) & 1u) + 0x7fffu;   // RNE
    return (unsigned short)(u >> 16);
}
__device__ __forceinline__ float bf2f(unsigned short h) {
    return __uint_as_float(((uint32_t)h) << 16);
}

// ---------------------------------------------------------------------------
// Host-side reproduction of np.random.RandomState(2).permutation(64):
// MT19937 init_genrand(2), Fisher-Yates with numpy random_interval
// (mask+rejection). Mask bit d = (perm[d] >= 38).
// ---------------------------------------------------------------------------
static uint64_t compute_mask_bits() {
    uint32_t mt[624];
    mt[0] = 2u;
    for (int i = 1; i < 624; i++)
        mt[i] = 1812433253u * (mt[i - 1] ^ (mt[i - 1] >> 30)) + (uint32_t)i;
    int mti = 624;
    auto genrand = [&]() -> uint32_t {
        if (mti >= 624) {
            for (int k = 0; k < 624; k++) {
                uint32_t y = (mt[k] & 0x80000000u) | (mt[(k + 1) % 624] & 0x7fffffffu);
                mt[k] = mt[(k + 397) % 624] ^ (y >> 1) ^ ((y & 1u) ? 2567483615u : 0u);
            }
            mti = 0;
        }
        uint32_t y = mt[mti++];
        y ^= y >> 11;
        y ^= (y << 7) & 2636928640u;
        y ^= (y << 15) & 4022730752u;
        y ^= y >> 18;
        return y;
    };
    int arr[64];
    for (int i = 0; i < 64; i++) arr[i] = i;
    for (int i = 63; i >= 1; i--) {
        uint32_t mask = (uint32_t)i;
        mask |= mask >> 1; mask |= mask >> 2; mask |= mask >> 4;
        mask |= mask >> 8; mask |= mask >> 16;
        uint32_t v;
        do { v = genrand() & mask; } while (v > (uint32_t)i);
        int tmp = arr[i]; arr[i] = arr[v]; arr[v] = tmp;
    }
    uint64_t bits = 0;
    for (int d = 0; d < 64; d++)
        if (arr[d] >= 38) bits |= (1ull << d);
    return bits;
}

// ---------------------------------------------------------------------------
// Output-row flag set + compacted list (rows read by the final dot).
// ---------------------------------------------------------------------------
__global__ void flag_kernel(const int* __restrict__ users, const int* __restrict__ items,
                            unsigned char* __restrict__ flag, int B, int U) {
    int i = blockIdx.x * 256 + threadIdx.x;
    if (i < B) flag[users[i]] = 1;
    else if (i < 2 * B) flag[U + items[i - B]] = 1;
}

__global__ void flist_kernel(const unsigned char* __restrict__ flag,
                             int* __restrict__ flist, int* __restrict__ fcount, int n) {
    int i = blockIdx.x * 256 + threadIdx.x;
    if (i < n && flag[i]) {
        int p = atomicAdd(fcount, 1);
        flist[p] = i;
    }
}

// ---------------------------------------------------------------------------
// Per-rating constant c1[r][j] = b1[r][j] + sum_k e_r[k] * W1[r][64+k][j].
// ---------------------------------------------------------------------------
__global__ void c1_kernel(const float* __restrict__ rating_emb, const float* __restrict__ W1,
                          const float* __restrict__ b1, float* __restrict__ c1_all) {
    int r = blockIdx.x;
    int t = threadIdx.x;  // 64 threads
    const float* W1r = W1 + (size_t)r * (128 * 64);
    float acc = b1[r * 64 + t];
    for (int k = 0; k < 64; k++)
        acc += rating_emb[r * 64 + k] * W1r[(64 + k) * 64 + t];
    c1_all[r * 64 + t] = acc;
}

// ---------------------------------------------------------------------------
// Build pass A (batched over ratings): LDS histogram over K=ceil(N/256) row
// buckets, then ONE global atomicAdd per (block,bucket) to reserve a range.
// ---------------------------------------------------------------------------
__global__ __launch_bounds__(1024) void bucket_count_kernel(
    const int* __restrict__ rows, int* __restrict__ gcnt,
    int* __restrict__ blockBase, int E, int K, int nb) {
    __shared__ int hist[2048];
    int r = blockIdx.y, blk = blockIdx.x, t = threadIdx.x;
    for (int i = t; i < K; i += 1024) hist[i] = 0;
    __syncthreads();
    size_t base = (size_t)r * E + (size_t)blk * EPB;
    int cnt = E - blk * EPB;
    if (cnt > EPB) cnt = EPB;
    for (int k = t; k < cnt; k += 1024)
        atomicAdd(&hist[rows[base + k] >> BSHIFT], 1);
    __syncthreads();
    for (int i = t; i < K; i += 1024) {
        int c = hist[i];
        int bb = (c > 0) ? atomicAdd(&gcnt[r * K + i], c) : 0;
        blockBase[((size_t)r * nb + blk) * K + i] = bb;
    }
}

// ---------------------------------------------------------------------------
// Exclusive scan of K bucket counts -> bptr[K+1] per rating (grid.x = R).
// ---------------------------------------------------------------------------
__global__ void bucket_scan_kernel(const int* __restrict__ gcnt,
                                   int* __restrict__ bptr, int K) {
    __shared__ int sh[256];
    int r = blockIdx.x;
    int t = threadIdx.x;
    int base = t * 8;
    int v[8];
    int s = 0;
    #pragma unroll
    for (int j = 0; j < 8; j++) {
        int idx = base + j;
        v[j] = (idx < K) ? gcnt[r * K + idx] : 0;
        s += v[j];
    }
    sh[t] = s;
    __syncthreads();
    for (int off = 1; off < 256; off <<= 1) {
        int x = (t >= off) ? sh[t - off] : 0;
        __syncthreads();
        sh[t] += x;
        __syncthreads();
    }
    int run = sh[t] - s;
    #pragma unroll
    for (int j = 0; j < 8; j++) {
        int idx = base + j;
        if (idx <= K) bptr[r * (K + 1) + idx] = run;
        run += v[j];
    }
}

// ---------------------------------------------------------------------------
// Build pass B: LDS-STAGED scatter into bucket-grouped rec (K <= 512).
// ---------------------------------------------------------------------------
__global__ __launch_bounds__(1024) void bucket_scatter_kernel(
    const int* __restrict__ rows, const int* __restrict__ cols,
    const float* __restrict__ vals, const int* __restrict__ bptr,
    const int* __restrict__ blockBase, uint2* __restrict__ rec,
    int E, int K, long long eStride, long long pStride,
    long long bbStride, long long rStride) {
    __shared__ uint2 staged[SUB];   // 32KB
    __shared__ int gaddr[SUB];      // 16KB final rec index per staged slot
    __shared__ int cursor[512];     // running global cursor per bucket
    __shared__ int lhist[512];      // per-subchunk count -> local base
    __shared__ int aux[512];        // scan scratch -> goff (=gbase-localbase)
    int r = blockIdx.y;
    const int* rows_r = rows + (size_t)r * eStride;
    const int* cols_r = cols + (size_t)r * eStride;
    const float* vals_r = vals + (size_t)r * eStride;
    const int* bptr_r = bptr + (size_t)r * pStride;
    const int* bb_r = blockBase + (size_t)r * bbStride;
    uint2* rec_r = rec + (size_t)r * rStride;
    int blk = blockIdx.x, t = threadIdx.x;
    if (t < 512)
        cursor[t] = (t < K) ? (bptr_r[t] + bb_r[(size_t)blk * K + t]) : 0;
    size_t base = (size_t)blk * EPB;
    int cnt = E - blk * EPB;
    if (cnt > EPB) cnt = EPB;
    for (int c0 = 0; c0 < cnt; c0 += SUB) {
        int scnt = cnt - c0;
        if (scnt > SUB) scnt = SUB;
        if (t < 512) lhist[t] = 0;
        __syncthreads();
        int bkt_[4], lpos_[4];
        uint2 rv_[4];
        #pragma unroll
        for (int q = 0; q < 4; q++) {
            int kk = (q << 10) + t;
            bkt_[q] = -1;
            if (kk < scnt) {
                size_t g = base + c0 + kk;
                int row = rows_r[g];
                int b = row >> BSHIFT;
                bkt_[q] = b;
                rv_[q] = make_uint2(((uint32_t)(row & (NRB - 1)) << KEYSHIFT) |
                                        (uint32_t)cols_r[g],
                                    __float_as_uint(vals_r[g]));
                lpos_[q] = atomicAdd(&lhist[b], 1);
            }
        }
        __syncthreads();
        int v = (t < 512) ? lhist[t] : 0;
        if (t < 512) aux[t] = v;
        __syncthreads();
        for (int off = 1; off < 512; off <<= 1) {
            int x = 0;
            if (t >= off && t < 512) x = aux[t - off];
            __syncthreads();
            if (t < 512) aux[t] += x;
            __syncthreads();
        }
        if (t < 512) {
            int ex = aux[t] - v;     // exclusive local base
            int gb = cursor[t];      // global base for this sub-chunk
            cursor[t] = gb + v;
            lhist[t] = ex;
            aux[t] = gb - ex;        // goff: gaddr = goff[b] + staged_idx
        }
        __syncthreads();
        #pragma unroll
        for (int q = 0; q < 4; q++) {
            if (bkt_[q] >= 0) {
                int sidx = lhist[bkt_[q]] + lpos_[q];
                staged[sidx] = rv_[q];
                gaddr[sidx] = aux[bkt_[q]] + sidx;
            }
        }
        __syncthreads();
        for (int i = t; i < scnt; i += 1024)
            rec_r[gaddr[i]] = staged[i];
        __syncthreads();
    }
}

// ---------------------------------------------------------------------------
// Build pass B legacy (direct scatter) — only used if K > 512.
// ---------------------------------------------------------------------------
__global__ __launch_bounds__(1024) void bucket_scatter_legacy(
    const int* __restrict__ rows, const int* __restrict__ cols,
    const float* __restrict__ vals, const int* __restrict__ bptr,
    const int* __restrict__ blockBase, uint2* __restrict__ rec,
    int E, int K, long long eStride, long long pStride,
    long long bbStride, long long rStride) {
    __shared__ int cursor[2048];
    int r = blockIdx.y;
    const int* rows_r = rows + (size_t)r * eStride;
    const int* cols_r = cols + (size_t)r * eStride;
    const float* vals_r = vals + (size_t)r * eStride;
    const int* bptr_r = bptr + (size_t)r * pStride;
    const int* bb_r = blockBase + (size_t)r * bbStride;
    uint2* rec_r = rec + (size_t)r * rStride;
    int blk = blockIdx.x, t = threadIdx.x;
    for (int i = t; i < K; i += 1024)
        cursor[i] = bptr_r[i] + bb_r[(size_t)blk * K + i];
    __syncthreads();
    size_t base = (size_t)blk * EPB;
    int cnt = E - blk * EPB;
    if (cnt > EPB) cnt = EPB;
    for (int k = t; k < cnt; k += 1024) {
        int row = rows_r[base + k];
        int b = row >> BSHIFT;
        int pos = atomicAdd(&cursor[b], 1);
        uint32_t key = ((uint32_t)(row & (NRB - 1)) << KEYSHIFT) | (uint32_t)cols_r[base + k];
        rec_r[pos] = make_uint2(key, __float_as_uint(vals_r[base + k]));
    }
}

// ---------------------------------------------------------------------------
// Build pass C: per-bucket counting sort by rel-row, FULLY IN LDS; srec
// written as one dense coalesced stream. Emits row_ptr.
// ---------------------------------------------------------------------------
__global__ __launch_bounds__(256) void bucket_sort_kernel(
    const uint2* __restrict__ rec, uint2* __restrict__ srec,
    const int* __restrict__ bptr, int* __restrict__ rp, int K, int N,
    long long rStride, long long pStride, long long rpStride) {
    __shared__ uint2 staged[CCAP];  // 24KB
    __shared__ int hist[NRB];
    __shared__ int excl[NRB];
    int r = blockIdx.y;
    const uint2* rec_r = rec + (size_t)r * rStride;
    uint2* srec_r = srec + (size_t)r * rStride;
    const int* bptr_r = bptr + (size_t)r * pStride;
    int* rp_r = rp + (size_t)r * rpStride;
    int b = blockIdx.x;
    int t = threadIdx.x;          // 256 threads == NRB
    hist[t] = 0;
    __syncthreads();
    int start = bptr_r[b], end = bptr_r[b + 1];
    int m = end - start;
    for (int e = start + t; e < end; e += 256)
        atomicAdd(&hist[rec_r[e].x >> KEYSHIFT], 1);
    __syncthreads();
    int v = hist[t];
    excl[t] = v;
    __syncthreads();
    for (int off = 1; off < 256; off <<= 1) {
        int x = (t >= off) ? excl[t - off] : 0;
        __syncthreads();
        excl[t] += x;
        __syncthreads();
    }
    int ex = excl[t] - v;
    excl[t] = ex;                 // own-slot overwrite, no cross-read yet
    hist[t] = 0;                  // reuse as cursors
    int row = b * NRB + t;
    if (row < N) rp_r[row] = start + ex;
    if (b == K - 1 && t == 0) rp_r[N] = bptr_r[K];
    __syncthreads();
    if (m <= CCAP) {
        for (int e = start + t; e < end; e += 256) {
            uint2 rr = rec_r[e];
            int rel = (int)(rr.x >> KEYSHIFT);
            int pos = excl[rel] + atomicAdd(&hist[rel], 1);
            staged[pos] = rr;
        }
        __syncthreads();
        for (int i = t; i < m; i += 256)
            srec_r[start + i] = staged[i];
    } else {
        for (int e = start + t; e < end; e += 256) {
            uint2 rr = rec_r[e];
            int rel = (int)(rr.x >> KEYSHIFT);
            int pos = start + excl[rel] + atomicAdd(&hist[rel], 1);
            srec_r[pos] = rr;
        }
    }
}

// ---------------------------------------------------------------------------
// MLP, ALL RATINGS IN ONE LAUNCH (R19). R4/R5/R6/R7 all hit a ~44us/launch
// floor with VALU-time == pure-FMA time (12us) -> per-launch stall structure
// is invariant. Fix the OUTER loop: stage X once, loop rr over ratings
// in-kernel (GEMM1 -> sT -> GEMM2 -> h_rr to its bufA slice), accumulate
// sum_r h in registers, single out_acc store. Removes 4x X-stage (100MB),
// 4 launch ramps, 4 out_acc RMW passes. Inner GEMMs = R7's proven form
// (lane=row, wave=16-col slice, W scalar-streamed via readfirstlane jbase).
// Fallback (nr=1) reproduces the old per-r init/RMW semantics exactly.
// ---------------------------------------------------------------------------
__global__ __launch_bounds__(256, 4) void mlp_kernel(
    const float* __restrict__ user_emb, const float* __restrict__ item_emb,
    const float* __restrict__ W1, const float* __restrict__ W2,
    const float* __restrict__ c1_all, const float* __restrict__ b2,
    unsigned short* __restrict__ prev, long long prevStride,
    float* __restrict__ out_acc, const unsigned char* __restrict__ flag,
    int r0, int nr, int n_rows, int U, int init) {
    __shared__ float sX[64 * 68];   // X, staged once (17.4KB)
    __shared__ float sT[64 * 68];   // per-rating hidden layer (17.4KB)

    int t = threadIdx.x;
    int lane = t & 63;
    int row0 = blockIdx.x * 64;
    int jbase = __builtin_amdgcn_readfirstlane((t >> 6) << 4);  // 0/16/32/48

    // Stage X: 1024 float4 / 256 threads = 4 each, coalesced global reads.
    #pragma unroll
    for (int q = 0; q < 4; q++) {
        int f = t + 256 * q;
        int i = f >> 4, c = (f & 15) * 4;
        int nrow = row0 + i;
        float4 xv = make_float4(0.f, 0.f, 0.f, 0.f);
        if (nrow < n_rows) {
            const float* src = (nrow < U) ? (user_emb + (size_t)nrow * 64)
                                          : (item_emb + (size_t)(nrow - U) * 64);
            xv = *(const float4*)(src + c);
        }
        *(float4*)(sX + i * 68 + c) = xv;
    }
    __syncthreads();

    int nrow = row0 + lane;
    bool valid = (nrow < n_rows);
    bool fl = valid && flag[nrow];
    float oa[16];
    #pragma unroll
    for (int i = 0; i < 16; i++) oa[i] = 0.f;

    for (int rr = r0; rr < r0 + nr; ++rr) {
        const float* W1r = W1 + (size_t)rr * (128 * 64);
        const float* W2r = W2 + (size_t)rr * (64 * 64);

        // acc = c1[rr][jbase..+15] (uniform scalar loads)
        const float* c1p = c1_all + rr * 64 + jbase;
        float4 a0 = *(const float4*)(c1p + 0);
        float4 a1 = *(const float4*)(c1p + 4);
        float4 a2 = *(const float4*)(c1p + 8);
        float4 a3 = *(const float4*)(c1p + 12);

        // GEMM1: X from sX, W1 scalar-streamed.
        #pragma unroll
        for (int m = 0; m < 16; m++) {
            float4 xv = *(const float4*)(sX + lane * 68 + 4 * m);
            const float* wk = W1r + (4 * m) * 64 + jbase;
            #pragma unroll
            for (int kk = 0; kk < 4; kk++) {
                float xs = (kk == 0) ? xv.x : (kk == 1) ? xv.y : (kk == 2) ? xv.z : xv.w;
                float4 w0 = *(const float4*)(wk + kk * 64 + 0);
                float4 w1 = *(const float4*)(wk + kk * 64 + 4);
                float4 w2 = *(const float4*)(wk + kk * 64 + 8);
                float4 w3 = *(const float4*)(wk + kk * 64 + 12);
                a0.x += xs * w0.x; a0.y += xs * w0.y; a0.z += xs * w0.z; a0.w += xs * w0.w;
                a1.x += xs * w1.x; a1.y += xs * w1.y; a1.z += xs * w1.z; a1.w += xs * w1.w;
                a2.x += xs * w2.x; a2.y += xs * w2.y; a2.z += xs * w2.z; a2.w += xs * w2.w;
                a3.x += xs * w3.x; a3.y += xs * w3.y; a3.z += xs * w3.z; a3.w += xs * w3.w;
            }
        }
        // leaky_relu
        a0.x = (a0.x >= 0.f) ? a0.x : 0.01f * a0.x;
        a0.y = (a0.y >= 0.f) ? a0.y : 0.01f * a0.y;
        a0.z = (a0.z >= 0.f) ? a0.z : 0.01f * a0.z;
        a0.w = (a0.w >= 0.f) ? a0.w : 0.01f * a0.w;
        a1.x = (a1.x >= 0.f) ? a1.x : 0.01f * a1.x;
        a1.y = (a1.y >= 0.f) ? a1.y : 0.01f * a1.y;
        a1.z = (a1.z >= 0.f) ? a1.z : 0.01f * a1.z;
        a1.w = (a1.w >= 0.f) ? a1.w : 0.01f * a1.w;
        a2.x = (a2.x >= 0.f) ? a2.x : 0.01f * a2.x;
        a2.y = (a2.y >= 0.f) ? a2.y : 0.01f * a2.y;
        a2.z = (a2.z >= 0.f) ? a2.z : 0.01f * a2.z;
        a2.w = (a2.w >= 0.f) ? a2.w : 0.01f * a2.w;
        a3.x = (a3.x >= 0.f) ? a3.x : 0.01f * a3.x;
        a3.y = (a3.y >= 0.f) ? a3.y : 0.01f * a3.y;
        a3.z = (a3.z >= 0.f) ? a3.z : 0.01f * a3.z;
        a3.w = (a3.w >= 0.f) ? a3.w : 0.01f * a3.w;

        *(float4*)(sT + lane * 68 + jbase + 0) = a0;
        *(float4*)(sT + lane * 68 + jbase + 4) = a1;
        *(float4*)(sT + lane * 68 + jbase + 8) = a2;
        *(float4*)(sT + lane * 68 + jbase + 12) = a3;
        __syncthreads();

        // acc = b2[rr][jbase..+15]
        const float* b2p = b2 + rr * 64 + jbase;
        a0 = *(const float4*)(b2p + 0);
        a1 = *(const float4*)(b2p + 4);
        a2 = *(const float4*)(b2p + 8);
        a3 = *(const float4*)(b2p + 12);

        // GEMM2: T from sT, W2 scalar-streamed.
        #pragma unroll
        for (int m = 0; m < 16; m++) {
            float4 xv = *(const float4*)(sT + lane * 68 + 4 * m);
            const float* wk = W2r + (4 * m) * 64 + jbase;
            #pragma unroll
            for (int kk = 0; kk < 4; kk++) {
                float xs = (kk == 0) ? xv.x : (kk == 1) ? xv.y : (kk == 2) ? xv.z : xv.w;
                float4 w0 = *(const float4*)(wk + kk * 64 + 0);
                float4 w1 = *(const float4*)(wk + kk * 64 + 4);
                float4 w2 = *(const float4*)(wk + kk * 64 + 8);
                float4 w3 = *(const float4*)(wk + kk * 64 + 12);
                a0.x += xs * w0.x; a0.y += xs * w0.y; a0.z += xs * w0.z; a0.w += xs * w0.w;
                a1.x += xs * w1.x; a1.y += xs * w1.y; a1.z += xs * w1.z; a1.w += xs * w1.w;
                a2.x += xs * w2.x; a2.y += xs * w2.y; a2.z += xs * w2.z; a2.w += xs * w2.w;
                a3.x += xs * w3.x; a3.y += xs * w3.y; a3.z += xs * w3.z; a3.w += xs * w3.w;
            }
        }

        // Epilogue per rating: h_rr -> prev slice (bf16); accumulate Σh.
        if (valid) {
            unsigned short* pp = prev + (size_t)rr * prevStride
                               + (size_t)nrow * 64 + jbase;
            ushort4 h0, h1, h2, h3;
            h0.x = f2bf(a0.x); h0.y = f2bf(a0.y); h0.z = f2bf(a0.z); h0.w = f2bf(a0.w);
            h1.x = f2bf(a1.x); h1.y = f2bf(a1.y); h1.z = f2bf(a1.z); h1.w = f2bf(a1.w);
            h2.x = f2bf(a2.x); h2.y = f2bf(a2.y); h2.z = f2bf(a2.z); h2.w = f2bf(a2.w);
            h3.x = f2bf(a3.x); h3.y = f2bf(a3.y); h3.z = f2bf(a3.z); h3.w = f2bf(a3.w);
            *(ushort4*)(pp + 0) = h0;
            *(ushort4*)(pp + 4) = h1;
            *(ushort4*)(pp + 8) = h2;
            *(ushort4*)(pp + 12) = h3;
            if (fl) {
                oa[0] += a0.x;  oa[1] += a0.y;  oa[2] += a0.z;  oa[3] += a0.w;
                oa[4] += a1.x;  oa[5] += a1.y;  oa[6] += a1.z;  oa[7] += a1.w;
                oa[8] += a2.x;  oa[9] += a2.y;  oa[10] += a2.z; oa[11] += a2.w;
                oa[12] += a3.x; oa[13] += a3.y; oa[14] += a3.z; oa[15] += a3.w;
            }
        }
        __syncthreads();   // protect sT before next rating overwrites it
    }

    if (fl) {
        float* o = out_acc + (size_t)nrow * 64 + jbase;
        if (init) {
            *(float4*)(o + 0) = make_float4(oa[0], oa[1], oa[2], oa[3]);
            *(float4*)(o + 4) = make_float4(oa[4], oa[5], oa[6], oa[7]);
            *(float4*)(o + 8) = make_float4(oa[8], oa[9], oa[10], oa[11]);
            *(float4*)(o + 12) = make_float4(oa[12], oa[13], oa[14], oa[15]);
        } else {
            float4 o0 = *(const float4*)(o + 0);
            float4 o1 = *(const float4*)(o + 4);
            float4 o2 = *(const float4*)(o + 8);
            float4 o3 = *(const float4*)(o + 12);
            o0.x += oa[0];  o0.y += oa[1];  o0.z += oa[2];  o0.w += oa[3];
            o1.x += oa[4];  o1.y += oa[5];  o1.z += oa[6];  o1.w += oa[7];
            o2.x += oa[8];  o2.y += oa[9];  o2.z += oa[10]; o2.w += oa[11];
            o3.x += oa[12]; o3.y += oa[13]; o3.z += oa[14]; o3.w += oa[15];
            *(float4*)(o + 0) = o0;
            *(float4*)(o + 4) = o1;
            *(float4*)(o + 8) = o2;
            *(float4*)(o + 12) = o3;
        }
    }
}

// ---------------------------------------------------------------------------
// Gather-SpMM (layers 0/1): wave = 1 row; 4 edge-groups x 16 lanes.
// Batched 4-edge window (ILP). bf16 operand, fp32 accumulation.
// ---------------------------------------------------------------------------
__global__ __launch_bounds__(256) void spmm_kernel(
    const unsigned short* __restrict__ prev, unsigned short* __restrict__ next,
    float* __restrict__ out_acc, const int* __restrict__ rp,
    const uint2* __restrict__ rec, const unsigned char* __restrict__ flag, int n) {
    int wave = (int)((blockIdx.x * (unsigned)blockDim.x + threadIdx.x) >> 6);
    int lane = threadIdx.x & 63;
    if (wave >= n) return;
    int sub = lane >> 4;      // edge group 0..3
    int dl = lane & 15;       // dims [dl*4, dl*4+4)
    int s = rp[wave], e2 = rp[wave + 1];
    float ax = 0.f, ay = 0.f, az = 0.f, aw = 0.f;
    for (int ew = s + sub; ew < e2; ew += 16) {
        int i1 = ew + 4, i2 = ew + 8, i3 = ew + 12;
        uint2 r0 = rec[ew];
        uint2 r1 = rec[i1 < e2 ? i1 : ew];
        uint2 r2 = rec[i2 < e2 ? i2 : ew];
        uint2 r3 = rec[i3 < e2 ? i3 : ew];
        float v0 = __uint_as_float(r0.y);
        float v1 = (i1 < e2) ? __uint_as_float(r1.y) : 0.f;
        float v2 = (i2 < e2) ? __uint_as_float(r2.y) : 0.f;
        float v3 = (i3 < e2) ? __uint_as_float(r3.y) : 0.f;
        ushort4 q0 = *(const ushort4*)(prev + (size_t)(r0.x & COLMASK) * 64 + dl * 4);
        ushort4 q1 = *(const ushort4*)(prev + (size_t)(r1.x & COLMASK) * 64 + dl * 4);
        ushort4 q2 = *(const ushort4*)(prev + (size_t)(r2.x & COLMASK) * 64 + dl * 4);
        ushort4 q3 = *(const ushort4*)(prev + (size_t)(r3.x & COLMASK) * 64 + dl * 4);
        ax += v0 * bf2f(q0.x) + v1 * bf2f(q1.x) + v2 * bf2f(q2.x) + v3 * bf2f(q3.x);
        ay += v0 * bf2f(q0.y) + v1 * bf2f(q1.y) + v2 * bf2f(q2.y) + v3 * bf2f(q3.y);
        az += v0 * bf2f(q0.z) + v1 * bf2f(q1.z) + v2 * bf2f(q2.z) + v3 * bf2f(q3.z);
        aw += v0 * bf2f(q0.w) + v1 * bf2f(q1.w) + v2 * bf2f(q2.w) + v3 * bf2f(q3.w);
    }
    ax += __shfl_xor(ax, 16); ay += __shfl_xor(ay, 16);
    az += __shfl_xor(az, 16); aw += __shfl_xor(aw, 16);
    ax += __shfl_xor(ax, 32); ay += __shfl_xor(ay, 32);
    az += __shfl_xor(az, 32); aw += __shfl_xor(aw, 32);
    if (sub == 0) {
        ushort4 nv;
        nv.x = f2bf(ax); nv.y = f2bf(ay); nv.z = f2bf(az); nv.w = f2bf(aw);
        *(ushort4*)(next + (size_t)wave * 64 + dl * 4) = nv;
    } else if (sub == 1 && flag[wave]) {
        float* o = out_acc + (size_t)wave * 64 + dl * 4;
        float4 ov = *(const float4*)o;
        ov.x += ax; ov.y += ay; ov.z += az; ov.w += aw;
        *(float4*)o = ov;
    }
}

// ---------------------------------------------------------------------------
// Layer-2 (masked) SpMM: only rows in flist. Same batched-edge form.
// ---------------------------------------------------------------------------
__global__ __launch_bounds__(256) void spmm_masked_kernel(
    const unsigned short* __restrict__ prev, float* __restrict__ out_acc,
    const int* __restrict__ rp, const uint2* __restrict__ rec,
    unsigned long long maskbits, const int* __restrict__ flist,
    const int* __restrict__ fcount) {
    int w = (int)((blockIdx.x * (unsigned)blockDim.x + threadIdx.x) >> 6);
    int lane = threadIdx.x & 63;
    if (w >= *fcount) return;
    int sub = lane >> 4;
    int dl = lane & 15;
    int row = flist[w];
    int s = rp[row], e2 = rp[row + 1];
    float ax = 0.f, ay = 0.f, az = 0.f, aw = 0.f;
    for (int ew = s + sub; ew < e2; ew += 16) {
        int i1 = ew + 4, i2 = ew + 8, i3 = ew + 12;
        uint2 r0 = rec[ew];
        uint2 r1 = rec[i1 < e2 ? i1 : ew];
        uint2 r2 = rec[i2 < e2 ? i2 : ew];
        uint2 r3 = rec[i3 < e2 ? i3 : ew];
        float v0 = __uint_as_float(r0.y);
        float v1 = (i1 < e2) ? __uint_as_float(r1.y) : 0.f;
        float v2 = (i2 < e2) ? __uint_as_float(r2.y) : 0.f;
        float v3 = (i3 < e2) ? __uint_as_float(r3.y) : 0.f;
        ushort4 q0 = *(const ushort4*)(prev + (size_t)(r0.x & COLMASK) * 64 + dl * 4);
        ushort4 q1 = *(const ushort4*)(prev + (size_t)(r1.x & COLMASK) * 64 + dl * 4);
        ushort4 q2 = *(const ushort4*)(prev + (size_t)(r2.x & COLMASK) * 64 + dl * 4);
        ushort4 q3 = *(const ushort4*)(prev + (size_t)(r3.x & COLMASK) * 64 + dl * 4);
        ax += v0 * bf2f(q0.x) + v1 * bf2f(q1.x) + v2 * bf2f(q2.x) + v3 * bf2f(q3.x);
        ay += v0 * bf2f(q0.y) + v1 * bf2f(q1.y) + v2 * bf2f(q2.y) + v3 * bf2f(q3.y);
        az += v0 * bf2f(q0.z) + v1 * bf2f(q1.z) + v2 * bf2f(q2.z) + v3 * bf2f(q3.z);
        aw += v0 * bf2f(q0.w) + v1 * bf2f(q1.w) + v2 * bf2f(q2.w) + v3 * bf2f(q3.w);
    }
    ax += __shfl_xor(ax, 16); ay += __shfl_xor(ay, 16);
    az += __shfl_xor(az, 16); aw += __shfl_xor(aw, 16);
    ax += __shfl_xor(ax, 32); ay += __shfl_xor(ay, 32);
    az += __shfl_xor(az, 32); aw += __shfl_xor(aw, 32);
    if (sub == 0) {
        ushort4 pq = *(const ushort4*)(prev + (size_t)row * 64 + dl * 4);
        float px = bf2f(pq.x), py = bf2f(pq.y), pz = bf2f(pq.z), pw = bf2f(pq.w);
        float rx = ((maskbits >> (dl * 4 + 0)) & 1ull) ? ax : px;
        float ry = ((maskbits >> (dl * 4 + 1)) & 1ull) ? ay : py;
        float rz = ((maskbits >> (dl * 4 + 2)) & 1ull) ? az : pz;
        float rw = ((maskbits >> (dl * 4 + 3)) & 1ull) ? aw : pw;
        float* o = out_acc + (size_t)row * 64 + dl * 4;
        float4 ov = *(const float4*)o;
        ov.x += rx; ov.y += ry; ov.z += rz; ov.w += rw;
        *(float4*)o = ov;
    }
}

// ---------------------------------------------------------------------------
// Final: out[b] = (1/R^2) * dot(out_acc[users[b]], out_acc[U+items[b]])
// ---------------------------------------------------------------------------
__global__ __launch_bounds__(256) void dot_kernel(
    const float* __restrict__ out_acc, const int* __restrict__ users,
    const int* __restrict__ items, float* __restrict__ out,
    int Bn, int U, float scale) {
    int w = (int)((blockIdx.x * (unsigned)blockDim.x + threadIdx.x) >> 6);
    int lane = threadIdx.x & 63;
    if (w >= Bn) return;
    int u = users[w], it = items[w];
    float a = out_acc[(size_t)u * 64 + lane];
    float c = out_acc[((size_t)(U + it)) * 64 + lane];
    float p = a * c;
    #pragma unroll
    for (int off = 32; off > 0; off >>= 1) p += __shfl_down(p, off);
    if (lane == 0) out[w] = p * scale;
}

// ---------------------------------------------------------------------------
extern "C" void kernel_launch(void* const* d_in, const int* in_sizes, int n_in,
                              void* d_out, int out_size, void* d_ws, size_t ws_size,
                              hipStream_t stream) {
    const int* users = (const int*)d_in[0];
    const int* items = (const int*)d_in[1];
    const float* user_emb = (const float*)d_in[2];
    const float* item_emb = (const float*)d_in[3];
    const float* rating_emb = (const float*)d_in[4];
    const float* W1 = (const float*)d_in[5];
    const float* b1 = (const float*)d_in[6];
    const float* W2 = (const float*)d_in[7];
    const float* b2 = (const float*)d_in[8];
    const int* rows = (const int*)d_in[9];
    const int* cols = (const int*)d_in[10];
    const float* vals = (const float*)d_in[11];
    float* out = (float*)d_out;

    const int Dd = 64;
    int U = in_sizes[2] / Dd;
    int I = in_sizes[3] / Dd;
    int R = in_sizes[4] / Dd;
    int N = U + I;
    int E = in_sizes[9] / R;
    int Bn = in_sizes[0];
    int K = (N + NRB - 1) / NRB;    // 256-row buckets; K+1 <= 2048
    int nb = (E + EPB - 1) / EPB;   // count/scatter blocks per rating

    auto al = [](size_t b) { return (b + 255) & ~(size_t)255; };
    size_t sliceA = al((size_t)N * 64 * 2);
    size_t bufA_all = al((size_t)R * N * 64 * 2);
    size_t common = al((size_t)N * 64 * 4) + sliceA /*bufB*/
        + al((size_t)R * K * 4)
        + al((size_t)R * (K + 1) * 4) + al((size_t)R * nb * K * 4)
        + al((size_t)R * (N + 1) * 4) + al((size_t)R * 64 * 4)
        + al((size_t)N) + al((size_t)2 * Bn * 4) + al(4);
    size_t rec_one = al((size_t)E * 8);
    size_t rec_all = al((size_t)E * 8 * R);
    int mlpb = 0, batched = 0;
    if (ws_size >= common + bufA_all + 2 * rec_all + 65536) {
        mlpb = 1; batched = 1;
    } else if (ws_size >= common + sliceA + 2 * rec_all + 65536) {
        batched = 1;
    }
    size_t bufAsz = mlpb ? bufA_all : sliceA;
    size_t recsz = batched ? rec_all : rec_one;

    char* p = (char*)d_ws;
    auto carve = [&](size_t bytes) -> char* {
        char* q = p;
        p += (bytes + 255) & ~(size_t)255;
        return q;
    };
    float* out_acc = (float*)carve((size_t)N * 64 * 4);
    unsigned short* bufA = (unsigned short*)carve(bufAsz);
    unsigned short* bufB = (unsigned short*)carve(sliceA);
    uint2* rec = (uint2*)carve(recsz);
    uint2* srec = (uint2*)carve(recsz);
    int* gcnt = (int*)carve((size_t)R * K * 4);
    int* bptr = (int*)carve((size_t)R * (K + 1) * 4);
    int* blockBase = (int*)carve((size_t)R * nb * K * 4);
    int* row_ptr = (int*)carve((size_t)R * (N + 1) * 4);
    float* c1_all = (float*)carve((size_t)R * 64 * 4);
    unsigned char* flag = (unsigned char*)carve((size_t)N);
    int* flist = (int*)carve((size_t)2 * Bn * 4);
    int* fcount = (int*)carve(4);

    uint64_t maskbits = compute_mask_bits();

    hipMemsetAsync(flag, 0, (size_t)N, stream);
    hipMemsetAsync(fcount, 0, 4, stream);
    hipMemsetAsync(gcnt, 0, (size_t)R * K * 4, stream);

    flag_kernel<<<(2 * Bn + 255) / 256, 256, 0, stream>>>(users, items, flag, Bn, U);
    flist_kernel<<<(N + 255) / 256, 256, 0, stream>>>(flag, flist, fcount, N);
    c1_kernel<<<R, 64, 0, stream>>>(rating_emb, W1, b1, c1_all);

    // Build pass A (batched over ratings) + per-rating scans
    dim3 cgrid(nb, R);
    bucket_count_kernel<<<cgrid, 1024, 0, stream>>>(rows, gcnt, blockBase, E, K, nb);
    bucket_scan_kernel<<<R, 256, 0, stream>>>(gcnt, bptr, K);

    if (batched) {
        dim3 sgrid(nb, R);
        if (K <= 512)
            bucket_scatter_kernel<<<sgrid, 1024, 0, stream>>>(
                rows, cols, vals, bptr, blockBase, rec, E, K,
                (long long)E, (long long)(K + 1), (long long)nb * K, (long long)E);
        else
            bucket_scatter_legacy<<<sgrid, 1024, 0, stream>>>(
                rows, cols, vals, bptr, blockBase, rec, E, K,
                (long long)E, (long long)(K + 1), (long long)nb * K, (long long)E);
        dim3 ogrid(K, R);
        bucket_sort_kernel<<<ogrid, 256, 0, stream>>>(
            rec, srec, bptr, row_ptr, K, N,
            (long long)E, (long long)(K + 1), (long long)(N + 1));
    }

    // All-ratings MLP in one launch (batched): X staged once, Σh single store.
    if (mlpb)
        mlp_kernel<<<(N + 63) / 64, 256, 0, stream>>>(
            user_emb, item_emb, W1, W2, c1_all, b2,
            bufA, (long long)N * 64, out_acc, flag, 0, R, N, U, 1);

    int spmm_blocks = (N + 3) / 4;
    int masked_blocks = (2 * Bn + 3) / 4;
    for (int r = 0; r < R; r++) {
        const int* bptr_r = bptr + (size_t)r * (K + 1);
        int* rp_r = row_ptr + (size_t)r * (N + 1);
        uint2* srec_r = batched ? (srec + (size_t)r * E) : srec;
        unsigned short* prev_r = mlpb ? (bufA + (size_t)r * N * 64) : bufA;

        if (!batched) {
            dim3 sgrid(nb, 1);
            if (K <= 512)
                bucket_scatter_kernel<<<sgrid, 1024, 0, stream>>>(
                    rows + (size_t)r * E, cols + (size_t)r * E, vals + (size_t)r * E,
                    bptr_r, blockBase + (size_t)r * nb * K, rec, E, K, 0, 0, 0, 0);
            else
                bucket_scatter_legacy<<<sgrid, 1024, 0, stream>>>(
                    rows + (size_t)r * E, cols + (size_t)r * E, vals + (size_t)r * E,
                    bptr_r, blockBase + (size_t)r * nb * K, rec, E, K, 0, 0, 0, 0);
            dim3 ogrid(K, 1);
            bucket_sort_kernel<<<ogrid, 256, 0, stream>>>(
                rec, srec, bptr_r, rp_r, K, N, 0, 0, 0);
        }

        if (!mlpb)
            mlp_kernel<<<(N + 63) / 64, 256, 0, stream>>>(
                user_emb, item_emb, W1, W2, c1_all, b2,
                bufA, 0, out_acc, flag, r, 1, N, U, (r == 0) ? 1 : 0);

        spmm_kernel<<<spmm_blocks, 256, 0, stream>>>(prev_r, bufB, out_acc, rp_r,
                                                     srec_r, flag, N);
        spmm_kernel<<<spmm_blocks, 256, 0, stream>>>(bufB, prev_r, out_acc, rp_r,
                                                     srec_r, flag, N);
        spmm_masked_kernel<<<masked_blocks, 256, 0, stream>>>(prev_r, out_acc, rp_r,
                                                              srec_r, maskbits,
                                                              flist, fcount);
    }

    float scale = 1.0f / (float)(R * R);
    dot_kernel<<<(Bn * 64 + 255) / 256, 256, 0, stream>>>(out_acc, users, items, out,
                                                          Bn, U, scale);
}